// Round 1
// baseline (2362.322 us; speedup 1.0000x reference)
//
#include <hip/hip_runtime.h>
#include <math.h>

// Problem constants (ViT-Base-ish)
#define BATCH 8
#define CIN 3
#define HIMG 256
#define WIMG 256
#define PATCH 8
#define DMODEL 768
#define DEPTH 8
#define HEADS 12
#define DHEAD 64
#define MLPDIM 3072
#define NTOK 1024              // (256/8)^2
#define INNER 768              // HEADS*DHEAD
#define MROWS (BATCH * NTOK)   // 8192
#define QKVS (3 * INNER)       // 2304
#define KPATCH (CIN * PATCH * PATCH)  // 192
#define LNEPS 1e-5f
// 0.125 (dh^-0.5) * log2(e): folded into Q so softmax uses exp2 (v_exp_f32)
#define QSCALE 0.18033688011112042f

typedef __attribute__((ext_vector_type(8))) short short8;  // 8 bf16 (4 VGPRs)
typedef __attribute__((ext_vector_type(4))) float v4f;     // MFMA accumulator

__device__ __forceinline__ float b2f(unsigned short u) {
  union { unsigned int i; float f; } x;
  x.i = (unsigned int)u << 16;
  return x.f;
}
__device__ __forceinline__ unsigned short f2b(float f) {
  union { float f; unsigned int i; } x;
  x.f = f;
  unsigned int r = x.i + 0x7FFFu + ((x.i >> 16) & 1u);  // RNE
  return (unsigned short)(r >> 16);
}
// pack 2 fp32 -> 2 bf16 in one u32, round-half-up (cheap: 4 VALU)
__device__ __forceinline__ unsigned int pkrh(float a, float b) {
  union { float f; unsigned int u; } x, y;
  x.f = a; y.f = b;
  return ((x.u + 0x8000u) >> 16) | ((y.u + 0x8000u) & 0xFFFF0000u);
}

// async 16B/lane global->LDS (wave-uniform LDS base + lane*16B)
#define GLL(gp, lp)                                                     \
  __builtin_amdgcn_global_load_lds(                                     \
      (const __attribute__((address_space(1))) void*)(gp),              \
      (__attribute__((address_space(3))) void*)(lp), 16, 0, 0)

// ---------------------------------------------------------------------------
// elementwise fp32 -> bf16 cast (w_conv: [768,192] already [N,K])
__global__ __launch_bounds__(256) void cast_kernel(
    const float* __restrict__ src, unsigned short* __restrict__ dst, int n) {
  int i = blockIdx.x * 256 + threadIdx.x;
  if (i < n) dst[i] = f2b(src[i]);
}

// transpose-cast: src fp32 [R,C] -> dst bf16 [C,R]. R,C multiples of 32.
// blockIdx.z selects a layer: both src and dst advance by R*C elements.
__global__ __launch_bounds__(256) void transpose_cast_kernel(
    const float* __restrict__ src, unsigned short* __restrict__ dst, int R,
    int C) {
  __shared__ unsigned short t[32][33];
  src += (size_t)blockIdx.z * R * C;
  dst += (size_t)blockIdx.z * R * C;
  int c0 = blockIdx.x * 32, r0 = blockIdx.y * 32;
  int tx = threadIdx.x & 31, ty = threadIdx.x >> 5;  // 32 x 8
#pragma unroll
  for (int u = 0; u < 4; ++u) {
    int r = r0 + ty + u * 8;
    t[ty + u * 8][tx] = f2b(src[(size_t)r * C + c0 + tx]);
  }
  __syncthreads();
#pragma unroll
  for (int u = 0; u < 4; ++u) {
    int c = c0 + ty + u * 8;
    dst[(size_t)c * R + r0 + tx] = t[tx][ty + u * 8];
  }
}

// V transpose per layer: qkv bf16 [MROWS][QKVS] V-part -> vt [B*H][64][1024]
__global__ __launch_bounds__(256) void vtrans_kernel(
    const unsigned short* __restrict__ qkv, unsigned short* __restrict__ vt) {
  __shared__ unsigned short t[32][33];
  int k0 = blockIdx.x * 32;   // key tile
  int d0 = blockIdx.y * 32;   // dim tile within head
  int bh = blockIdx.z;        // b*HEADS+h
  int b = bh / HEADS, h = bh % HEADS;
  int tx = threadIdx.x & 31, ty = threadIdx.x >> 5;
  const unsigned short* src =
      qkv + (size_t)(b * NTOK) * QKVS + 2 * INNER + h * DHEAD;
#pragma unroll
  for (int u = 0; u < 4; ++u)
    t[ty + u * 8][tx] = src[(size_t)(k0 + ty + u * 8) * QKVS + d0 + tx];
  __syncthreads();
  unsigned short* dst = vt + ((size_t)bh * DHEAD + d0) * NTOK + k0;
#pragma unroll
  for (int u = 0; u < 4; ++u)
    dst[(size_t)(ty + u * 8) * NTOK + tx] = t[tx][ty + u * 8];
}

// im2col -> bf16: x [B,C,H,W] -> A [MROWS, 192]
__global__ __launch_bounds__(256) void im2col_kernel(
    const float* __restrict__ x, unsigned short* __restrict__ A) {
  int idx = blockIdx.x * 256 + threadIdx.x;
  if (idx >= MROWS * KPATCH) return;
  int m = idx / KPATCH, k = idx % KPATCH;
  int b = m / NTOK, n = m % NTOK;
  int ph = n / 32, pw = n % 32;
  int c = k / 64, r = k % 64;
  int py = r / 8, px = r % 8;
  A[idx] =
      f2b(x[((size_t)(b * CIN + c) * HIMG + ph * 8 + py) * WIMG + pw * 8 + px]);
}

// ---------------------------------------------------------------------------
// Legacy bf16 MFMA GEMM (single-buffer 2-barrier skeleton). Kept only for the
// patch-embed GEMM (K=192, tiny). See gemm8_kernel for the main path.
template <int EPI, int OB, int MT>
__global__ __launch_bounds__(256) void mfma_gemm_kernel(
    const unsigned short* __restrict__ Ag, const unsigned short* __restrict__ Bt,
    const float* __restrict__ bias, const float* __restrict__ res,
    void* __restrict__ Cg, int Mdim, int Ndim, int Kdim) {
  constexpr int MI = MT / 32;               // m fragment tiles per wave (4|2)
  constexpr int RA = MT / 4;                // A rows staged per wave (32|16)
  constexpr int NCA = RA / 8;               // A GLL chunks per wave (4|2)
  __shared__ __align__(16) unsigned short Asm[MT * 64];
  __shared__ __align__(16) unsigned short Bsm[128 * 64];
  int tid = threadIdx.x;
  int lane = tid & 63, wv = tid >> 6;

  // XCD-aware swizzle (1-D grid of (M/MT)*(N/128) blocks)
  int Nt = Ndim / 128;
  int mchunk = (Mdim / MT) >> 3;
  int bid = blockIdx.x;
  int xcd = bid & 7;
  int j = bid >> 3;
  int m0 = (xcd * mchunk + j / Nt) * MT;
  int n0 = (j % Nt) * 128;

  v4f acc[MI][4] = {};

  int sr8 = lane >> 3;
  int sc8 = ((lane & 7) ^ sr8) * 8;
  const unsigned short* Aw = Ag + (size_t)(m0 + RA * wv + sr8) * Kdim + sc8;
  const unsigned short* Bw = Bt + (size_t)(n0 + 32 * wv + sr8) * Kdim + sc8;
  unsigned short* As0 = Asm + (RA * wv) * 64;
  unsigned short* Bs0 = Bsm + (32 * wv) * 64;

  int quad = lane >> 4, lr = lane & 15;
  int fr0 = (wv >> 1) * (MI * 16);
  int fc0 = (wv & 1) * 64;
  int xcol = (quad ^ (lr & 7)) * 8;  // swizzled col offset (s=0); s=1: ^32
  const unsigned short* Afr = Asm + (fr0 + lr) * 64;
  const unsigned short* Bfr = Bsm + (fc0 + lr) * 64;

  for (int k0 = 0; k0 < Kdim; k0 += 64) {
#pragma unroll
    for (int c = 0; c < NCA; ++c)
      GLL(Aw + k0 + (size_t)(8 * c) * Kdim, As0 + c * 8 * 64);
#pragma unroll
    for (int c = 0; c < 4; ++c)
      GLL(Bw + k0 + (size_t)(8 * c) * Kdim, Bs0 + c * 8 * 64);
    __syncthreads();
#pragma unroll
    for (int s = 0; s < 2; ++s) {
      int xo = xcol ^ (s * 32);
      short8 af[MI], bf[4];
#pragma unroll
      for (int i = 0; i < MI; ++i)
        af[i] = *(const short8*)(Afr + i * 16 * 64 + xo);
#pragma unroll
      for (int n = 0; n < 4; ++n)
        bf[n] = *(const short8*)(Bfr + n * 16 * 64 + xo);
#pragma unroll
      for (int i = 0; i < MI; ++i)
#pragma unroll
        for (int n = 0; n < 4; ++n)
          acc[i][n] = __builtin_amdgcn_mfma_f32_16x16x32_bf16(
              af[i], bf[n], acc[i][n], 0, 0, 0);
    }
    __syncthreads();
  }

  float* Cf = (float*)Cg;
  unsigned short* Cb = (unsigned short*)Cg;
#pragma unroll
  for (int i = 0; i < MI; ++i) {
#pragma unroll
    for (int n = 0; n < 4; ++n) {
      int ncol = n0 + fc0 + 16 * n + lr;
#pragma unroll
      for (int reg = 0; reg < 4; ++reg) {
        int mrow = m0 + fr0 + 16 * i + quad * 4 + reg;
        float v = acc[i][n][reg];
        if (EPI == 2 || EPI == 3 || EPI == 4) v += bias[ncol];
        if (EPI == 2) v += res[(size_t)mrow * Ndim + ncol];
        if (EPI == 3) {
          float u = v * (0.7978845608028654f + 0.035677408136300125f * v * v);
          float a = fminf(fmaxf(u * 2.8853900817779268f, -60.f), 60.f);
          float E = __builtin_amdgcn_exp2f(a);
          v = v * E * __builtin_amdgcn_rcpf(E + 1.0f);
        }
        if (EPI == 4) v += res[(size_t)(mrow % NTOK) * Ndim + ncol];
        if (EPI == 5 && ncol < INNER) v *= QSCALE;
        if (OB)
          Cb[(size_t)mrow * Ndim + ncol] = f2b(v);
        else
          Cf[(size_t)mrow * Ndim + ncol] = v;
      }
    }
  }
}

// ---------------------------------------------------------------------------
// Phase-interleaved MFMA GEMM: C[M,N] = A[M,K] @ Bt[N,K]^T.
// BM=256, BN=128, BK=64. 512 threads = 8 waves (4M x 2N), 64x64 out/wave.
// 3-deep LDS ring (3 x 48KB, dynamic), prefetch 2 K-tiles ahead via GLL,
// counted vmcnt(6) once per K-tile (never 0 in steady state), raw s_barrier
// (no implicit vmcnt drain), setprio around MFMA clusters.
// Schedule safety:
//  - RAW: tile t's stages are confirmed by vmcnt(6) in phase B(t-1), one
//    barrier BEFORE the first ds_read of tile t (cross-wave visibility via
//    that barrier).
//  - WAR: stages for t+2 (ring slot of t-1) are issued >=2 barriers after the
//    last ds_read of t-1 (phase B(t-1) reads -> lgkmcnt(0) -> barrier pair).
// LDS uses the proven chunk-XOR swizzle (chunk ^= row&7) with pre-swizzled
// GLL global source; b128 frag reads are conflict-free per 8-lane phase.
#define ABUF (256 * 64)
#define BBUF (128 * 64)
#define SM8B ((3 * ABUF + 3 * BBUF) * 2)  // 147456 bytes dynamic LDS

template <int EPI, int OB>
__global__ __launch_bounds__(512, 2) void gemm8_kernel(
    const unsigned short* __restrict__ Ag, const unsigned short* __restrict__ Bt,
    const float* __restrict__ bias, const float* __restrict__ res,
    void* __restrict__ Cg, int Mdim, int Ndim, int Kdim) {
  extern __shared__ __align__(16) unsigned short sm8[];
  unsigned short* As = sm8;               // 3 bufs of [256][64]
  unsigned short* Bs = sm8 + 3 * ABUF;    // 3 bufs of [128][64]
  int tid = threadIdx.x;
  int lane = tid & 63, wv = tid >> 6;
  int wm = wv >> 1, wn = wv & 1;          // 4M x 2N wave grid
  int quad = lane >> 4, lr = lane & 15;

  int Nt = Ndim / 128;
  int mchunk = (Mdim / 256) >> 3;
  int bid = blockIdx.x;
  int xcd = bid & 7;
  int j = bid >> 3;
  int m0 = (xcd * mchunk + j / Nt) * 256;
  int n0 = (j % Nt) * 128;
  int NTI = Kdim >> 6;  // K-tiles (>= 2)

  // staging: GLL round = 64 rows (8 rows/wave); source col-group XOR-permuted
  int sr8 = lane >> 3;
  int sc8 = ((lane & 7) ^ sr8) * 8;
  const unsigned short* Aw = Ag + (size_t)(m0 + wv * 8 + sr8) * Kdim + sc8;
  const unsigned short* Bw = Bt + (size_t)(n0 + wv * 8 + sr8) * Kdim + sc8;
  unsigned short* AsW = As + (wv * 8) * 64;
  unsigned short* BsW = Bs + (wv * 8) * 64;

  // fragment reads: row (..+lr)*64, chunk (s*4+quad)^(lr&7)
  int xq = (quad ^ (lr & 7)) * 8;
  const unsigned short* Afr = As + (wm * 64 + lr) * 64;
  const unsigned short* Bfr = Bs + (wn * 64 + lr) * 64;

  v4f acc[4][4] = {};

  // prologue: stage K-tiles 0 and 1 into ring slots 0,1
#pragma unroll
  for (int t = 0; t < 2; ++t) {
#pragma unroll
    for (int r = 0; r < 4; ++r)
      GLL(Aw + t * 64 + (size_t)(64 * r) * Kdim, AsW + t * ABUF + r * 64 * 64);
#pragma unroll
    for (int r = 0; r < 2; ++r)
      GLL(Bw + t * 64 + (size_t)(64 * r) * Kdim, BsW + t * BBUF + r * 64 * 64);
  }
  asm volatile("s_waitcnt vmcnt(6)" ::: "memory");  // tile 0 landed
  __builtin_amdgcn_s_barrier();

  int rb = 0, sb = 2;  // read slot, stage slot
  for (int t = 0; t < NTI; ++t) {
    const unsigned short* Afb = Afr + rb * ABUF;
    const unsigned short* Bfb = Bfr + rb * BBUF;
    const unsigned short* Ak = Aw + (t + 2) * 64;
    const unsigned short* Bk = Bw + (t + 2) * 64;
    unsigned short* Ad = AsW + sb * ABUF;
    unsigned short* Bd = BsW + sb * BBUF;
    bool st = (t + 2 < NTI);

    // ---- phase A: frags (A all, B n-half 0), stage A rounds 0-2 of t+2 ----
    short8 af[2][4], bf[2][2];
#pragma unroll
    for (int s2 = 0; s2 < 2; ++s2) {
      int xo = xq ^ (s2 * 32);
#pragma unroll
      for (int m = 0; m < 4; ++m)
        af[s2][m] = *(const short8*)(Afb + m * 16 * 64 + xo);
#pragma unroll
      for (int n = 0; n < 2; ++n)
        bf[s2][n] = *(const short8*)(Bfb + n * 16 * 64 + xo);
    }
    if (st) {
#pragma unroll
      for (int r = 0; r < 3; ++r)
        GLL(Ak + (size_t)(64 * r) * Kdim, Ad + r * 64 * 64);
    }
    __builtin_amdgcn_s_barrier();
    asm volatile("s_waitcnt lgkmcnt(0)" ::: "memory");
    __builtin_amdgcn_sched_barrier(0);
    __builtin_amdgcn_s_setprio(1);
#pragma unroll
    for (int s2 = 0; s2 < 2; ++s2)
#pragma unroll
      for (int m = 0; m < 4; ++m)
#pragma unroll
        for (int n = 0; n < 2; ++n)
          acc[m][n] = __builtin_amdgcn_mfma_f32_16x16x32_bf16(
              af[s2][m], bf[s2][n], acc[m][n], 0, 0, 0);
    __builtin_amdgcn_s_setprio(0);
    __builtin_amdgcn_s_barrier();

    // ---- phase B: frags (B n-half 1), stage A round 3 + B rounds 0-1 ------
    short8 bg[2][2];
#pragma unroll
    for (int s2 = 0; s2 < 2; ++s2) {
      int xo = xq ^ (s2 * 32);
#pragma unroll
      for (int n = 0; n < 2; ++n)
        bg[s2][n] = *(const short8*)(Bfb + (32 + n * 16) * 64 + xo);
    }
    if (st) {
      GLL(Ak + (size_t)(64 * 3) * Kdim, Ad + 3 * 64 * 64);
#pragma unroll
      for (int r = 0; r < 2; ++r)
        GLL(Bk + (size_t)(64 * r) * Kdim, Bd + r * 64 * 64);
    }
    if (t + 2 < NTI) {
      asm volatile("s_waitcnt vmcnt(6)" ::: "memory");  // tile t+1 landed
    } else if (t + 1 < NTI) {
      asm volatile("s_waitcnt vmcnt(0)" ::: "memory");  // tail drain
    }
    __builtin_amdgcn_s_barrier();
    asm volatile("s_waitcnt lgkmcnt(0)" ::: "memory");
    __builtin_amdgcn_sched_barrier(0);
    __builtin_amdgcn_s_setprio(1);
#pragma unroll
    for (int s2 = 0; s2 < 2; ++s2)
#pragma unroll
      for (int m = 0; m < 4; ++m)
#pragma unroll
        for (int n = 0; n < 2; ++n)
          acc[m][n + 2] = __builtin_amdgcn_mfma_f32_16x16x32_bf16(
              af[s2][m], bg[s2][n], acc[m][n + 2], 0, 0, 0);
    __builtin_amdgcn_s_setprio(0);
    __builtin_amdgcn_s_barrier();

    rb = (rb == 2) ? 0 : rb + 1;
    sb = (sb == 2) ? 0 : sb + 1;
  }

  // epilogue: C/D layout col=lane&15, row=quad*4+reg
  float* Cf = (float*)Cg;
  unsigned short* Cb = (unsigned short*)Cg;
#pragma unroll
  for (int i = 0; i < 4; ++i) {
#pragma unroll
    for (int n = 0; n < 4; ++n) {
      int ncol = n0 + wn * 64 + 16 * n + lr;
#pragma unroll
      for (int reg = 0; reg < 4; ++reg) {
        int mrow = m0 + wm * 64 + 16 * i + quad * 4 + reg;
        float v = acc[i][n][reg];
        if (EPI == 2 || EPI == 3) v += bias[ncol];
        if (EPI == 2) v += res[(size_t)mrow * Ndim + ncol];
        if (EPI == 3) {
          float u = v * (0.7978845608028654f + 0.035677408136300125f * v * v);
          float a = fminf(fmaxf(u * 2.8853900817779268f, -60.f), 60.f);
          float E = __builtin_amdgcn_exp2f(a);
          v = v * E * __builtin_amdgcn_rcpf(E + 1.0f);
        }
        if (EPI == 5 && ncol < INNER) v *= QSCALE;
        if (OB)
          Cb[(size_t)mrow * Ndim + ncol] = f2b(v);
        else
          Cf[(size_t)mrow * Ndim + ncol] = v;
      }
    }
  }
}

// ---------------------------------------------------------------------------
// LayerNorm over last dim (768), fp32 in -> bf16 out. One block per row.
__global__ __launch_bounds__(256) void ln_kernel(
    const float* __restrict__ x, const float* __restrict__ w,
    const float* __restrict__ b, unsigned short* __restrict__ y) {
  int row = blockIdx.x;
  const float* xr = x + (size_t)row * DMODEL;
  unsigned short* yr = y + (size_t)row * DMODEL;
  int tid = threadIdx.x;
  float v0 = xr[tid], v1 = xr[tid + 256], v2 = xr[tid + 512];
  float s = v0 + v1 + v2;
  __shared__ float red[4];
#pragma unroll
  for (int off = 32; off >= 1; off >>= 1) s += __shfl_xor(s, off, 64);
  if ((tid & 63) == 0) red[tid >> 6] = s;
  __syncthreads();
  float mean = (red[0] + red[1] + red[2] + red[3]) * (1.0f / DMODEL);
  float d0 = v0 - mean, d1 = v1 - mean, d2 = v2 - mean;
  float sq = d0 * d0 + d1 * d1 + d2 * d2;
  __syncthreads();
#pragma unroll
  for (int off = 32; off >= 1; off >>= 1) sq += __shfl_xor(sq, off, 64);
  if ((tid & 63) == 0) red[tid >> 6] = sq;
  __syncthreads();
  float var = (red[0] + red[1] + red[2] + red[3]) * (1.0f / DMODEL);
  float rs = rsqrtf(var + LNEPS);
  yr[tid] = f2b(d0 * rs * w[tid] + b[tid]);
  yr[tid + 256] = f2b(d1 * rs * w[tid + 256] + b[tid + 256]);
  yr[tid + 512] = f2b(d2 * rs * w[tid + 512] + b[tid + 512]);
}

// ---------------------------------------------------------------------------
// MFMA flash attention. Block = (128 q-rows, head, batch); 4 waves x 32 q.
// S^T = K @ Q^T (C/D col = q), online softmax via in-wave shuffles, P packed
// bf16 into per-wave LDS in A-fragment layout, O = P @ V with pre-transposed
// V (vtg). Q pre-scaled by QSCALE in qkv GEMM -> softmax uses native exp2.
// LDS buffers use stride 64 + chunk-XOR swizzle (chunk ^= row&7): every b128
// frag read / int4 store spans all 32 banks per 8-lane phase (kills the
// 8-way conflicts the PSTR=72 layout had: 5.55M/dispatch).
__global__ __launch_bounds__(256) void attn_kernel(
    const unsigned short* __restrict__ qkv,
    const unsigned short* __restrict__ vtg, unsigned short* __restrict__ o) {
  __shared__ __align__(16) unsigned short Ks[64 * 64];
  __shared__ __align__(16) unsigned short Vs[64 * 64];
  __shared__ __align__(16) unsigned short Pl[4][32 * 64];
  int tid = threadIdx.x;
  int lane = tid & 63, wv = tid >> 6;
  int quad = lane >> 4, lr = lane & 15;
  int q0 = blockIdx.x * 128, hh = blockIdx.y, bb = blockIdx.z;

  const unsigned short* qg =
      qkv + (size_t)(bb * NTOK + q0 + wv * 32) * QKVS + hh * DHEAD;
  const unsigned short* kg =
      qkv + (size_t)(bb * NTOK) * QKVS + INNER + hh * DHEAD;
  const unsigned short* vg = vtg + (size_t)(bb * HEADS + hh) * DHEAD * NTOK;
  unsigned short* Pw = Pl[wv];

  int srow = lane >> 3, soff = (lane & 7) * 8;
  int xs = ((lane & 7) ^ srow) * 8;      // swizzled store col
  int xq = (quad ^ (lr & 7)) * 8;        // swizzled frag-read col (s=0)

#pragma unroll
  for (int p = 0; p < 4; ++p) {
    int r = p * 8 + srow;
    *(int4*)(Pw + r * 64 + xs) = *(const int4*)(qg + (size_t)r * QKVS + soff);
  }
  short8 qf[2][2];
#pragma unroll
  for (int n = 0; n < 2; ++n)
#pragma unroll
    for (int s = 0; s < 2; ++s)
      qf[n][s] = *(const short8*)(Pw + (n * 16 + lr) * 64 + (xq ^ (s * 32)));

  v4f oac[2][4] = {};
  float m_i[2] = {-1e30f, -1e30f};
  float l_i[2] = {0.f, 0.f};

  for (int t = 0; t < NTOK / 64; ++t) {
    __syncthreads();
#pragma unroll
    for (int p = 0; p < 2; ++p) {
      int r = wv * 16 + p * 8 + srow;
      *(int4*)(Ks + r * 64 + xs) =
          *(const int4*)(kg + (size_t)(t * 64 + r) * QKVS + soff);
      *(int4*)(Vs + r * 64 + xs) =
          *(const int4*)(vg + (size_t)r * NTOK + t * 64 + soff);
    }
    __syncthreads();

    v4f sac[4][2] = {};
#pragma unroll
    for (int s = 0; s < 2; ++s) {
      short8 kf[4];
#pragma unroll
      for (int mt = 0; mt < 4; ++mt)
        kf[mt] = *(const short8*)(Ks + (mt * 16 + lr) * 64 + (xq ^ (s * 32)));
#pragma unroll
      for (int mt = 0; mt < 4; ++mt)
#pragma unroll
        for (int n = 0; n < 2; ++n)
          sac[mt][n] = __builtin_amdgcn_mfma_f32_16x16x32_bf16(
              kf[mt], qf[n][s], sac[mt][n], 0, 0, 0);
    }

#pragma unroll
    for (int n = 0; n < 2; ++n) {
      float mx = -1e30f;
#pragma unroll
      for (int mt = 0; mt < 4; ++mt)
#pragma unroll
        for (int r = 0; r < 4; ++r) mx = fmaxf(mx, sac[mt][n][r]);
      mx = fmaxf(mx, __shfl_xor(mx, 16, 64));
      mx = fmaxf(mx, __shfl_xor(mx, 32, 64));
      float mnew = fmaxf(m_i[n], mx);
      float alpha = __builtin_amdgcn_exp2f(m_i[n] - mnew);
      m_i[n] = mnew;
      float sum = 0.f;
#pragma unroll
      for (int mt = 0; mt < 4; ++mt) {
#pragma unroll
        for (int r = 0; r < 4; ++r) {
          float p = __builtin_amdgcn_exp2f(sac[mt][n][r] - mnew);
          sac[mt][n][r] = p;
          sum += p;
        }
        *(uint2*)(Pw + (n * 16 + lr) * 64 +
                  (((mt * 2 + (quad >> 1)) ^ (lr & 7)) * 8) + (quad & 1) * 4) =
            make_uint2(pkrh(sac[mt][n][0], sac[mt][n][1]),
                       pkrh(sac[mt][n][2], sac[mt][n][3]));
      }
      sum += __shfl_xor(sum, 16, 64);
      sum += __shfl_xor(sum, 32, 64);
      l_i[n] = l_i[n] * alpha + sum;
#pragma unroll
      for (int r = 0; r < 4; ++r) {
        float ao = __shfl(alpha, quad * 4 + r, 64);
#pragma unroll
        for (int j = 0; j < 4; ++j) oac[n][j][r] *= ao;
      }
    }

#pragma unroll
    for (int s = 0; s < 2; ++s) {
      short8 pf[2], vf[4];
#pragma unroll
      for (int i = 0; i < 2; ++i)
        pf[i] = *(const short8*)(Pw + (i * 16 + lr) * 64 + (xq ^ (s * 32)));
#pragma unroll
      for (int j = 0; j < 4; ++j)
        vf[j] = *(const short8*)(Vs + (j * 16 + lr) * 64 + (xq ^ (s * 32)));
#pragma unroll
      for (int i = 0; i < 2; ++i)
#pragma unroll
        for (int j = 0; j < 4; ++j)
          oac[i][j] = __builtin_amdgcn_mfma_f32_16x16x32_bf16(
              pf[i], vf[j], oac[i][j], 0, 0, 0);
    }
  }

  unsigned short* ob =
      o + (size_t)(bb * NTOK + q0 + wv * 32) * INNER + hh * DHEAD;
#pragma unroll
  for (int i = 0; i < 2; ++i) {
    float inv = 1.0f / l_i[i];
#pragma unroll
    for (int r = 0; r < 4; ++r) {
      float il = __shfl(inv, quad * 4 + r, 64);
      int row = i * 16 + quad * 4 + r;
#pragma unroll
      for (int j = 0; j < 4; ++j)
        ob[(size_t)row * INNER + 16 * j + lr] = f2b(oac[i][j][r] * il);
    }
  }
}

// ---------------------------------------------------------------------------
extern "C" void kernel_launch(void* const* d_in, const int* in_sizes, int n_in,
                              void* d_out, int out_size, void* d_ws,
                              size_t ws_size, hipStream_t stream) {
  const float* x      = (const float*)d_in[0];
  const float* w_conv = (const float*)d_in[1];
  const float* b_conv = (const float*)d_in[2];
  const float* pos    = (const float*)d_in[3];
  const float* ln1w   = (const float*)d_in[4];
  const float* ln1b   = (const float*)d_in[5];
  const float* qkvw   = (const float*)d_in[6];
  const float* outw   = (const float*)d_in[7];
  const float* outb   = (const float*)d_in[8];
  const float* ln2w   = (const float*)d_in[9];
  const float* ln2b   = (const float*)d_in[10];
  const float* w1     = (const float*)d_in[11];
  const float* b1     = (const float*)d_in[12];
  const float* w2     = (const float*)d_in[13];
  const float* b2     = (const float*)d_in[14];

  char* ws = (char*)d_ws;
  float* outp = (float*)d_out;
  dim3 blk(256);
  dim3 blk8(512);

  // Allow 144KB dynamic LDS on the phase-interleaved GEMM (once per process)
  static bool attr_done = false;
  if (!attr_done) {
    (void)hipFuncSetAttribute(
        reinterpret_cast<const void*>(&gemm8_kernel<5, 1>),
        hipFuncAttributeMaxDynamicSharedMemorySize, SM8B);
    (void)hipFuncSetAttribute(
        reinterpret_cast<const void*>(&gemm8_kernel<2, 0>),
        hipFuncAttributeMaxDynamicSharedMemorySize, SM8B);
    (void)hipFuncSetAttribute(
        reinterpret_cast<const void*>(&gemm8_kernel<3, 1>),
        hipFuncAttributeMaxDynamicSharedMemorySize, SM8B);
    attr_done = true;
  }

  // Common buffers
  float* h            = (float*)(ws + 0);                 // 25,165,824 B
  unsigned short* big = (unsigned short*)(ws + 25165824); // 50,331,648 B
  unsigned short* y   = (unsigned short*)(ws + 75497472); // 12,582,912 B

  // Batched-weight layout (needs 214,204,416 B); fallback = per-layer.
  const size_t NEEDED = 214204416;
  bool batched = ws_size >= NEEDED;

  unsigned short *vt, *wc, *wqa, *woa, *w1a, *w2a;  // batched
  unsigned short *wq_f, *wo_f, *w1_f, *w2_f;        // fallback per-layer
  if (batched) {
    vt  = (unsigned short*)(ws + 88080384);   // 12,582,912 B
    wc  = (unsigned short*)(ws + 100663296);  //    294,912 B
    wqa = (unsigned short*)(ws + 100958208);  // 28,311,552 B
    woa = (unsigned short*)(ws + 129269760);  //  9,437,184 B
    w1a = (unsigned short*)(ws + 138706944);  // 37,748,736 B
    w2a = (unsigned short*)(ws + 176455680);  // 37,748,736 B
    wq_f = wo_f = w1_f = w2_f = nullptr;
  } else {
    wq_f = (unsigned short*)(ws + 88080384);  //  3,538,944 B
    wo_f = (unsigned short*)(ws + 91619328);  //  1,179,648 B
    w1_f = (unsigned short*)(ws + 92798976);  //  4,718,592 B
    w2_f = (unsigned short*)(ws + 97517568);  //  4,718,592 B
    wc   = (unsigned short*)(ws + 102236160); //    294,912 B
    vt   = (unsigned short*)(ws + 102531072); // 12,582,912 B
    wqa = woa = w1a = w2a = nullptr;
  }

  cast_kernel<<<dim3((DMODEL * KPATCH + 255) / 256), blk, 0, stream>>>(
      w_conv, wc, DMODEL * KPATCH);
  im2col_kernel<<<dim3((MROWS * KPATCH + 255) / 256), blk, 0, stream>>>(x, big);
  // patch embed: [8192,192] @ wc[768,192]^T + b_conv + pos -> h fp32 (K=192)
  mfma_gemm_kernel<4, 0, 64>
      <<<dim3((MROWS / 64) * (DMODEL / 128)), blk, 0, stream>>>(
          big, wc, b_conv, pos, h, MROWS, DMODEL, KPATCH);

  if (batched) {  // all-layer weight transposes, one dispatch per type
    transpose_cast_kernel<<<dim3(QKVS / 32, DMODEL / 32, DEPTH), blk, 0,
                            stream>>>(qkvw, wqa, DMODEL, QKVS);
    transpose_cast_kernel<<<dim3(DMODEL / 32, INNER / 32, DEPTH), blk, 0,
                            stream>>>(outw, woa, INNER, DMODEL);
    transpose_cast_kernel<<<dim3(MLPDIM / 32, DMODEL / 32, DEPTH), blk, 0,
                            stream>>>(w1, w1a, DMODEL, MLPDIM);
    transpose_cast_kernel<<<dim3(DMODEL / 32, MLPDIM / 32, DEPTH), blk, 0,
                            stream>>>(w2, w2a, MLPDIM, DMODEL);
  }

  for (int l = 0; l < DEPTH; ++l) {
    unsigned short* wq = batched ? wqa + (size_t)l * DMODEL * QKVS : wq_f;
    unsigned short* wo = batched ? woa + (size_t)l * INNER * DMODEL : wo_f;
    unsigned short* w1t = batched ? w1a + (size_t)l * DMODEL * MLPDIM : w1_f;
    unsigned short* w2t = batched ? w2a + (size_t)l * MLPDIM * DMODEL : w2_f;
    if (!batched) {
      transpose_cast_kernel<<<dim3(QKVS / 32, DMODEL / 32), blk, 0, stream>>>(
          qkvw + (size_t)l * DMODEL * QKVS, wq, DMODEL, QKVS);
    }
    ln_kernel<<<dim3(MROWS), blk, 0, stream>>>(h, ln1w + l * DMODEL,
                                               ln1b + l * DMODEL, y);
    gemm8_kernel<5, 1>
        <<<dim3((MROWS / 256) * (QKVS / 128)), blk8, SM8B, stream>>>(
            y, wq, nullptr, nullptr, big, MROWS, QKVS, DMODEL);
    vtrans_kernel<<<dim3(NTOK / 32, DHEAD / 32, BATCH * HEADS), blk, 0,
                    stream>>>(big, vt);
    attn_kernel<<<dim3(NTOK / 128, HEADS, BATCH), blk, 0, stream>>>(big, vt, y);
    if (!batched) {
      transpose_cast_kernel<<<dim3(DMODEL / 32, INNER / 32), blk, 0, stream>>>(
          outw + (size_t)l * INNER * DMODEL, wo, INNER, DMODEL);
    }
    gemm8_kernel<2, 0>
        <<<dim3((MROWS / 256) * (DMODEL / 128)), blk8, SM8B, stream>>>(
            y, wo, outb + l * DMODEL, h, h, MROWS, DMODEL, INNER);
    ln_kernel<<<dim3(MROWS), blk, 0, stream>>>(h, ln2w + l * DMODEL,
                                               ln2b + l * DMODEL, y);
    if (!batched) {
      transpose_cast_kernel<<<dim3(MLPDIM / 32, DMODEL / 32), blk, 0, stream>>>(
          w1 + (size_t)l * DMODEL * MLPDIM, w1t, DMODEL, MLPDIM);
    }
    gemm8_kernel<3, 1>
        <<<dim3((MROWS / 256) * (MLPDIM / 128)), blk8, SM8B, stream>>>(
            y, w1t, b1 + l * MLPDIM, nullptr, big, MROWS, MLPDIM, DMODEL);
    if (!batched) {
      transpose_cast_kernel<<<dim3(DMODEL / 32, MLPDIM / 32), blk, 0, stream>>>(
          w2 + (size_t)l * MLPDIM * DMODEL, w2t, MLPDIM, DMODEL);
    }
    float* dst = (l == DEPTH - 1) ? outp : h;
    gemm8_kernel<2, 0>
        <<<dim3((MROWS / 256) * (DMODEL / 128)), blk8, SM8B, stream>>>(
            big, w2t, b2 + l * DMODEL, h, dst, MROWS, DMODEL, MLPDIM);
  }
}

// Round 3
// 2326.259 us; speedup vs baseline: 1.0155x; 1.0155x over previous
//
#include <hip/hip_runtime.h>
#include <math.h>

// Problem constants (ViT-Base-ish)
#define BATCH 8
#define CIN 3
#define HIMG 256
#define WIMG 256
#define PATCH 8
#define DMODEL 768
#define DEPTH 8
#define HEADS 12
#define DHEAD 64
#define MLPDIM 3072
#define NTOK 1024              // (256/8)^2
#define INNER 768              // HEADS*DHEAD
#define MROWS (BATCH * NTOK)   // 8192
#define QKVS (3 * INNER)       // 2304
#define KPATCH (CIN * PATCH * PATCH)  // 192
#define LNEPS 1e-5f
// 0.125 (dh^-0.5) * log2(e): folded into Q so softmax uses exp2 (v_exp_f32)
#define QSCALE 0.18033688011112042f

typedef __attribute__((ext_vector_type(8))) short short8;  // 8 bf16 (4 VGPRs)
typedef __attribute__((ext_vector_type(4))) float v4f;     // MFMA accumulator

__device__ __forceinline__ float b2f(unsigned short u) {
  union { unsigned int i; float f; } x;
  x.i = (unsigned int)u << 16;
  return x.f;
}
__device__ __forceinline__ unsigned short f2b(float f) {
  union { float f; unsigned int i; } x;
  x.f = f;
  unsigned int r = x.i + 0x7FFFu + ((x.i >> 16) & 1u);  // RNE
  return (unsigned short)(r >> 16);
}
// pack 2 fp32 -> 2 bf16 in one u32, round-half-up (cheap: 4 VALU)
__device__ __forceinline__ unsigned int pkrh(float a, float b) {
  union { float f; unsigned int u; } x, y;
  x.f = a; y.f = b;
  return ((x.u + 0x8000u) >> 16) | ((y.u + 0x8000u) & 0xFFFF0000u);
}

// async 16B/lane global->LDS (wave-uniform LDS base + lane*16B)
#define GLL(gp, lp)                                                     \
  __builtin_amdgcn_global_load_lds(                                     \
      (const __attribute__((address_space(1))) void*)(gp),              \
      (__attribute__((address_space(3))) void*)(lp), 16, 0, 0)

// ---------------------------------------------------------------------------
// elementwise fp32 -> bf16 cast (w_conv: [768,192] already [N,K])
__global__ __launch_bounds__(256) void cast_kernel(
    const float* __restrict__ src, unsigned short* __restrict__ dst, int n) {
  int i = blockIdx.x * 256 + threadIdx.x;
  if (i < n) dst[i] = f2b(src[i]);
}

// transpose-cast: src fp32 [R,C] -> dst bf16 [C,R]. R,C multiples of 32.
// blockIdx.z selects a layer: both src and dst advance by R*C elements.
__global__ __launch_bounds__(256) void transpose_cast_kernel(
    const float* __restrict__ src, unsigned short* __restrict__ dst, int R,
    int C) {
  __shared__ unsigned short t[32][33];
  src += (size_t)blockIdx.z * R * C;
  dst += (size_t)blockIdx.z * R * C;
  int c0 = blockIdx.x * 32, r0 = blockIdx.y * 32;
  int tx = threadIdx.x & 31, ty = threadIdx.x >> 5;  // 32 x 8
#pragma unroll
  for (int u = 0; u < 4; ++u) {
    int r = r0 + ty + u * 8;
    t[ty + u * 8][tx] = f2b(src[(size_t)r * C + c0 + tx]);
  }
  __syncthreads();
#pragma unroll
  for (int u = 0; u < 4; ++u) {
    int c = c0 + ty + u * 8;
    dst[(size_t)c * R + r0 + tx] = t[tx][ty + u * 8];
  }
}

// V transpose per layer: qkv bf16 [MROWS][QKVS] V-part -> vt [B*H][64][1024]
__global__ __launch_bounds__(256) void vtrans_kernel(
    const unsigned short* __restrict__ qkv, unsigned short* __restrict__ vt) {
  __shared__ unsigned short t[32][33];
  int k0 = blockIdx.x * 32;   // key tile
  int d0 = blockIdx.y * 32;   // dim tile within head
  int bh = blockIdx.z;        // b*HEADS+h
  int b = bh / HEADS, h = bh % HEADS;
  int tx = threadIdx.x & 31, ty = threadIdx.x >> 5;
  const unsigned short* src =
      qkv + (size_t)(b * NTOK) * QKVS + 2 * INNER + h * DHEAD;
#pragma unroll
  for (int u = 0; u < 4; ++u)
    t[ty + u * 8][tx] = src[(size_t)(k0 + ty + u * 8) * QKVS + d0 + tx];
  __syncthreads();
  unsigned short* dst = vt + ((size_t)bh * DHEAD + d0) * NTOK + k0;
#pragma unroll
  for (int u = 0; u < 4; ++u)
    dst[(size_t)(ty + u * 8) * NTOK + tx] = t[tx][ty + u * 8];
}

// im2col -> bf16: x [B,C,H,W] -> A [MROWS, 192]
__global__ __launch_bounds__(256) void im2col_kernel(
    const float* __restrict__ x, unsigned short* __restrict__ A) {
  int idx = blockIdx.x * 256 + threadIdx.x;
  if (idx >= MROWS * KPATCH) return;
  int m = idx / KPATCH, k = idx % KPATCH;
  int b = m / NTOK, n = m % NTOK;
  int ph = n / 32, pw = n % 32;
  int c = k / 64, r = k % 64;
  int py = r / 8, px = r % 8;
  A[idx] =
      f2b(x[((size_t)(b * CIN + c) * HIMG + ph * 8 + py) * WIMG + pw * 8 + px]);
}

// ---------------------------------------------------------------------------
// Proven 2-barrier bf16 MFMA GEMM (3 blocks/CU). Used for patch embed and the
// N=768 GEMMs (out-proj, mlp2) where 256-wide tiles would idle 25% of CUs.
// Also the fallback for qkv/mlp1 if the 128KB dynamic-LDS opt-in fails.
template <int EPI, int OB, int MT>
__global__ __launch_bounds__(256) void mfma_gemm_kernel(
    const unsigned short* __restrict__ Ag, const unsigned short* __restrict__ Bt,
    const float* __restrict__ bias, const float* __restrict__ res,
    void* __restrict__ Cg, int Mdim, int Ndim, int Kdim) {
  constexpr int MI = MT / 32;               // m fragment tiles per wave (4|2)
  constexpr int RA = MT / 4;                // A rows staged per wave (32|16)
  constexpr int NCA = RA / 8;               // A GLL chunks per wave (4|2)
  __shared__ __align__(16) unsigned short Asm[MT * 64];
  __shared__ __align__(16) unsigned short Bsm[128 * 64];
  int tid = threadIdx.x;
  int lane = tid & 63, wv = tid >> 6;

  // XCD-aware swizzle (1-D grid of (M/MT)*(N/128) blocks)
  int Nt = Ndim / 128;
  int mchunk = (Mdim / MT) >> 3;
  int bid = blockIdx.x;
  int xcd = bid & 7;
  int j = bid >> 3;
  int m0 = (xcd * mchunk + j / Nt) * MT;
  int n0 = (j % Nt) * 128;

  v4f acc[MI][4] = {};

  int sr8 = lane >> 3;
  int sc8 = ((lane & 7) ^ sr8) * 8;
  const unsigned short* Aw = Ag + (size_t)(m0 + RA * wv + sr8) * Kdim + sc8;
  const unsigned short* Bw = Bt + (size_t)(n0 + 32 * wv + sr8) * Kdim + sc8;
  unsigned short* As0 = Asm + (RA * wv) * 64;
  unsigned short* Bs0 = Bsm + (32 * wv) * 64;

  int quad = lane >> 4, lr = lane & 15;
  int fr0 = (wv >> 1) * (MI * 16);
  int fc0 = (wv & 1) * 64;
  int xcol = (quad ^ (lr & 7)) * 8;  // swizzled col offset (s=0); s=1: ^32
  const unsigned short* Afr = Asm + (fr0 + lr) * 64;
  const unsigned short* Bfr = Bsm + (fc0 + lr) * 64;

  for (int k0 = 0; k0 < Kdim; k0 += 64) {
#pragma unroll
    for (int c = 0; c < NCA; ++c)
      GLL(Aw + k0 + (size_t)(8 * c) * Kdim, As0 + c * 8 * 64);
#pragma unroll
    for (int c = 0; c < 4; ++c)
      GLL(Bw + k0 + (size_t)(8 * c) * Kdim, Bs0 + c * 8 * 64);
    __syncthreads();
#pragma unroll
    for (int s = 0; s < 2; ++s) {
      int xo = xcol ^ (s * 32);
      short8 af[MI], bf[4];
#pragma unroll
      for (int i = 0; i < MI; ++i)
        af[i] = *(const short8*)(Afr + i * 16 * 64 + xo);
#pragma unroll
      for (int n = 0; n < 4; ++n)
        bf[n] = *(const short8*)(Bfr + n * 16 * 64 + xo);
#pragma unroll
      for (int i = 0; i < MI; ++i)
#pragma unroll
        for (int n = 0; n < 4; ++n)
          acc[i][n] = __builtin_amdgcn_mfma_f32_16x16x32_bf16(
              af[i], bf[n], acc[i][n], 0, 0, 0);
    }
    __syncthreads();
  }

  float* Cf = (float*)Cg;
  unsigned short* Cb = (unsigned short*)Cg;
#pragma unroll
  for (int i = 0; i < MI; ++i) {
#pragma unroll
    for (int n = 0; n < 4; ++n) {
      int ncol = n0 + fc0 + 16 * n + lr;
#pragma unroll
      for (int reg = 0; reg < 4; ++reg) {
        int mrow = m0 + fr0 + 16 * i + quad * 4 + reg;
        float v = acc[i][n][reg];
        if (EPI == 2 || EPI == 3 || EPI == 4) v += bias[ncol];
        if (EPI == 2) v += res[(size_t)mrow * Ndim + ncol];
        if (EPI == 3) {
          float u = v * (0.7978845608028654f + 0.035677408136300125f * v * v);
          float a = fminf(fmaxf(u * 2.8853900817779268f, -60.f), 60.f);
          float E = __builtin_amdgcn_exp2f(a);
          v = v * E * __builtin_amdgcn_rcpf(E + 1.0f);
        }
        if (EPI == 4) v += res[(size_t)(mrow % NTOK) * Ndim + ncol];
        if (EPI == 5 && ncol < INNER) v *= QSCALE;
        if (OB)
          Cb[(size_t)mrow * Ndim + ncol] = f2b(v);
        else
          Cf[(size_t)mrow * Ndim + ncol] = v;
      }
    }
  }
}

// ---------------------------------------------------------------------------
// m201-style 8-phase 256x256 GEMM (plain-HIP port of the verified template).
// BK=64, 512 thr = 8 waves (2M x 4N), per-wave out 128x64 (acc[8][4]).
// 2 K-tiles per iter; LDS = 2 bufs x (A 256x64 + B 256x64) bf16 = 128 KiB.
// Each phase: {ds_read subtile || 2x GLL half-tile stage -> s_barrier ->
// lgkmcnt(0)+sched_barrier -> setprio(1) 16 MFMA setprio(0) -> s_barrier}.
// Counted vmcnt(4) ONLY at phases 4 and 8 (2 half-tiles stay in flight).
// Static stage order per iter (t=2i read ph1-4 from buf0, t+1 ph5-8 buf1):
//   ph1: A0(t+1)->buf1   ph2: A1(t+1)->buf1   ph3: B0(t+2)->buf0
//   ph4: B1(t+2)->buf0   ph5: A0(t+2)->buf0   ph6: A1(t+2)->buf0
//   ph7: B0(t+3)->buf1   ph8: B1(t+3)->buf1
// Safety (derived): ph4's vmcnt(4) retires B(t+1)[prev ph7/8] + A(t+1)[ph1/2]
// before ph5 reads buf1; ph8's vmcnt(4) retires tile t+2 before next-iter ph1
// reads buf0. Every GLL that overwrites an LDS region is issued >=1 barrier
// after the reading wave's own lgkmcnt(0) retired its ds_reads. Tail iter:
// ph4 drains vmcnt(0), ph5-8 stage nothing. Barriers are wave-uniform.
#define ABUF8 (256 * 64)
#define BBUF8 (256 * 64)
#define SM8PH (2 * (ABUF8 + BBUF8) * 2)  // 131072 bytes dynamic LDS

template <int EPI, int OB>
__global__ __launch_bounds__(512, 2) void gemm8ph_kernel(
    const unsigned short* __restrict__ Ag, const unsigned short* __restrict__ Bt,
    const float* __restrict__ bias, void* __restrict__ Cg, int Mdim, int Ndim,
    int Kdim) {
  extern __shared__ __align__(16) unsigned short sm8[];
  unsigned short* As = sm8;               // [2][256][64]
  unsigned short* Bs = sm8 + 2 * ABUF8;   // [2][256][64]
  int tid = threadIdx.x;
  int lane = tid & 63, wv = tid >> 6;
  int wm = wv >> 2, wn = wv & 3;          // 2M x 4N wave grid
  int quad = lane >> 4, lr = lane & 15;

  int Nt = Ndim >> 8;
  int mchunk = (Mdim >> 8) >> 3;
  int bid = blockIdx.x;
  int xcd = bid & 7, j = bid >> 3;
  int m0 = (xcd * mchunk + j / Nt) << 8;
  int n0 = (j % Nt) << 8;
  int NTI = Kdim >> 6;  // K-tiles, even, >= 4

  // staging: GLL round = 64 rows (8/wave); source col-group XOR-permuted
  int sr8 = lane >> 3;
  int sc8 = ((lane & 7) ^ sr8) * 8;
  const unsigned short* Aw = Ag + (size_t)(m0 + wv * 8 + sr8) * Kdim + sc8;
  const unsigned short* Bw = Bt + (size_t)(n0 + wv * 8 + sr8) * Kdim + sc8;
  unsigned short* AsW = As + (wv * 8) * 64;
  unsigned short* BsW = Bs + (wv * 8) * 64;

  // fragment reads
  int xq = (quad ^ (lr & 7)) * 8;
  const unsigned short* Afr = As + (wm * 128 + lr) * 64;   // buf0
  const unsigned short* Bfr = Bs + (wn * 64 + lr) * 64;    // buf0
  const unsigned short* Afr1 = Afr + ABUF8;                // buf1
  const unsigned short* Bfr1 = Bfr + BBUF8;                // buf1

  v4f acc[8][4] = {};
  short8 af[2][4], bf0[2][2], bf1[2][2];

#define STG_A8(buf, tile, half)                                           \
  do {                                                                    \
    GLL(Aw + (size_t)((half) * 128) * Kdim + (tile) * 64,                 \
        AsW + (buf) * ABUF8 + ((half) * 128) * 64);                       \
    GLL(Aw + (size_t)((half) * 128 + 64) * Kdim + (tile) * 64,            \
        AsW + (buf) * ABUF8 + ((half) * 128 + 64) * 64);                  \
  } while (0)
#define STG_B8(buf, tile, half)                                           \
  do {                                                                    \
    GLL(Bw + (size_t)((half) * 128) * Kdim + (tile) * 64,                 \
        BsW + (buf) * BBUF8 + ((half) * 128) * 64);                       \
    GLL(Bw + (size_t)((half) * 128 + 64) * Kdim + (tile) * 64,            \
        BsW + (buf) * BBUF8 + ((half) * 128 + 64) * 64);                  \
  } while (0)

  auto rd_af = [&](const unsigned short* base, int mb) {
#pragma unroll
    for (int s = 0; s < 2; ++s)
#pragma unroll
      for (int m = 0; m < 4; ++m)
        af[s][m] =
            *(const short8*)(base + (mb + m * 16) * 64 + (xq ^ (s * 32)));
  };
  auto rd_bf0 = [&](const unsigned short* base, int nb) {
#pragma unroll
    for (int s = 0; s < 2; ++s)
#pragma unroll
      for (int n = 0; n < 2; ++n)
        bf0[s][n] =
            *(const short8*)(base + (nb + n * 16) * 64 + (xq ^ (s * 32)));
  };
  auto rd_bf1 = [&](const unsigned short* base, int nb) {
#pragma unroll
    for (int s = 0; s < 2; ++s)
#pragma unroll
      for (int n = 0; n < 2; ++n)
        bf1[s][n] =
            *(const short8*)(base + (nb + n * 16) * 64 + (xq ^ (s * 32)));
  };
  auto mfma0 = [&](int mb, int nb) {  // af x bf0
#pragma unroll
    for (int s = 0; s < 2; ++s)
#pragma unroll
      for (int m = 0; m < 4; ++m)
#pragma unroll
        for (int n = 0; n < 2; ++n)
          acc[mb + m][nb + n] = __builtin_amdgcn_mfma_f32_16x16x32_bf16(
              af[s][m], bf0[s][n], acc[mb + m][nb + n], 0, 0, 0);
  };
  auto mfma1 = [&](int mb, int nb) {  // af x bf1
#pragma unroll
    for (int s = 0; s < 2; ++s)
#pragma unroll
      for (int m = 0; m < 4; ++m)
#pragma unroll
        for (int n = 0; n < 2; ++n)
          acc[mb + m][nb + n] = __builtin_amdgcn_mfma_f32_16x16x32_bf16(
              af[s][m], bf1[s][n], acc[mb + m][nb + n], 0, 0, 0);
  };
  auto mfma_begin = [&]() {
    __builtin_amdgcn_s_barrier();
    asm volatile("s_waitcnt lgkmcnt(0)" ::: "memory");
    __builtin_amdgcn_sched_barrier(0);
    __builtin_amdgcn_s_setprio(1);
  };
  auto mfma_end = [&]() {
    __builtin_amdgcn_s_setprio(0);
    __builtin_amdgcn_s_barrier();
  };

  // prologue: tile0 -> buf0 (B0,B1,A0,A1); tile1 B -> buf1 (B0,B1)
  STG_B8(0, 0, 0);
  STG_B8(0, 0, 1);
  STG_A8(0, 0, 0);
  STG_A8(0, 0, 1);
  STG_B8(1, 1, 0);
  STG_B8(1, 1, 1);
  asm volatile("s_waitcnt vmcnt(4)" ::: "memory");  // tile0 landed
  __builtin_amdgcn_s_barrier();

  int NI = NTI >> 1;
  for (int i = 0; i < NI; ++i) {
    int t1 = 2 * i + 1, t2 = 2 * i + 2, t3 = 2 * i + 3;
    bool st = t2 < NTI;

    // ---- phase 1 ----
    rd_af(Afr, 0);
    rd_bf0(Bfr, 0);
    STG_A8(1, t1, 0);
    mfma_begin();
    mfma0(0, 0);
    mfma_end();
    // ---- phase 2 ----
    rd_bf1(Bfr, 32);
    STG_A8(1, t1, 1);
    mfma_begin();
    mfma1(0, 2);
    mfma_end();
    // ---- phase 3 ----
    rd_af(Afr, 64);
    if (st) STG_B8(0, t2, 0);
    mfma_begin();
    mfma0(4, 0);
    mfma_end();
    // ---- phase 4 ----
    if (st) {
      STG_B8(0, t2, 1);
      asm volatile("s_waitcnt vmcnt(4)" ::: "memory");  // tile t1 landed
    } else {
      asm volatile("s_waitcnt vmcnt(0)" ::: "memory");  // tail drain
    }
    mfma_begin();
    mfma1(4, 2);
    mfma_end();
    // ---- phase 5 ----
    rd_af(Afr1, 0);
    rd_bf0(Bfr1, 0);
    if (st) STG_A8(0, t2, 0);
    mfma_begin();
    mfma0(0, 0);
    mfma_end();
    // ---- phase 6 ----
    rd_bf1(Bfr1, 32);
    if (st) STG_A8(0, t2, 1);
    mfma_begin();
    mfma1(0, 2);
    mfma_end();
    // ---- phase 7 ----
    rd_af(Afr1, 64);
    if (st) STG_B8(1, t3, 0);
    mfma_begin();
    mfma0(4, 0);
    mfma_end();
    // ---- phase 8 ----
    if (st) {
      STG_B8(1, t3, 1);
      asm volatile("s_waitcnt vmcnt(4)" ::: "memory");  // tile t2 landed
    }
    mfma_begin();
    mfma1(4, 2);
    mfma_end();
  }
#undef STG_A8
#undef STG_B8

  // epilogue: C/D layout col=lane&15, row=quad*4+reg
  float* Cf = (float*)Cg;
  unsigned short* Cb = (unsigned short*)Cg;
#pragma unroll
  for (int i = 0; i < 8; ++i) {
#pragma unroll
    for (int n = 0; n < 4; ++n) {
      int ncol = n0 + wn * 64 + 16 * n + lr;
#pragma unroll
      for (int reg = 0; reg < 4; ++reg) {
        int mrow = m0 + wm * 128 + 16 * i + quad * 4 + reg;
        float v = acc[i][n][reg];
        if (EPI == 3) {
          v += bias[ncol];
          float u = v * (0.7978845608028654f + 0.035677408136300125f * v * v);
          float a = fminf(fmaxf(u * 2.8853900817779268f, -60.f), 60.f);
          float E = __builtin_amdgcn_exp2f(a);
          v = v * E * __builtin_amdgcn_rcpf(E + 1.0f);
        }
        if (EPI == 5 && ncol < INNER) v *= QSCALE;
        if (OB)
          Cb[(size_t)mrow * Ndim + ncol] = f2b(v);
        else
          Cf[(size_t)mrow * Ndim + ncol] = v;
      }
    }
  }
}

// ---------------------------------------------------------------------------
// LayerNorm over last dim (768), fp32 in -> bf16 out. One block per row.
__global__ __launch_bounds__(256) void ln_kernel(
    const float* __restrict__ x, const float* __restrict__ w,
    const float* __restrict__ b, unsigned short* __restrict__ y) {
  int row = blockIdx.x;
  const float* xr = x + (size_t)row * DMODEL;
  unsigned short* yr = y + (size_t)row * DMODEL;
  int tid = threadIdx.x;
  float v0 = xr[tid], v1 = xr[tid + 256], v2 = xr[tid + 512];
  float s = v0 + v1 + v2;
  __shared__ float red[4];
#pragma unroll
  for (int off = 32; off >= 1; off >>= 1) s += __shfl_xor(s, off, 64);
  if ((tid & 63) == 0) red[tid >> 6] = s;
  __syncthreads();
  float mean = (red[0] + red[1] + red[2] + red[3]) * (1.0f / DMODEL);
  float d0 = v0 - mean, d1 = v1 - mean, d2 = v2 - mean;
  float sq = d0 * d0 + d1 * d1 + d2 * d2;
  __syncthreads();
#pragma unroll
  for (int off = 32; off >= 1; off >>= 1) sq += __shfl_xor(sq, off, 64);
  if ((tid & 63) == 0) red[tid >> 6] = sq;
  __syncthreads();
  float var = (red[0] + red[1] + red[2] + red[3]) * (1.0f / DMODEL);
  float rs = rsqrtf(var + LNEPS);
  yr[tid] = f2b(d0 * rs * w[tid] + b[tid]);
  yr[tid + 256] = f2b(d1 * rs * w[tid + 256] + b[tid + 256]);
  yr[tid + 512] = f2b(d2 * rs * w[tid + 512] + b[tid + 512]);
}

// ---------------------------------------------------------------------------
// MFMA flash attention. Block = (128 q-rows, head, batch); 4 waves x 32 q.
// S^T = K @ Q^T (C/D col = q), online softmax via in-wave shuffles, P packed
// bf16 into per-wave LDS in A-fragment layout, O = P @ V with pre-transposed
// V (vtg). Q pre-scaled by QSCALE in qkv GEMM -> softmax uses native exp2.
// Defer-max (T13): skip the O-rescale + alpha shuffles when the per-tile max
// grows <= 8 in exp2 domain (P bounded by 256; fp32 l/oac tolerate).
__global__ __launch_bounds__(256) void attn_kernel(
    const unsigned short* __restrict__ qkv,
    const unsigned short* __restrict__ vtg, unsigned short* __restrict__ o) {
  __shared__ __align__(16) unsigned short Ks[64 * 64];
  __shared__ __align__(16) unsigned short Vs[64 * 64];
  __shared__ __align__(16) unsigned short Pl[4][32 * 64];
  int tid = threadIdx.x;
  int lane = tid & 63, wv = tid >> 6;
  int quad = lane >> 4, lr = lane & 15;
  int q0 = blockIdx.x * 128, hh = blockIdx.y, bb = blockIdx.z;

  const unsigned short* qg =
      qkv + (size_t)(bb * NTOK + q0 + wv * 32) * QKVS + hh * DHEAD;
  const unsigned short* kg =
      qkv + (size_t)(bb * NTOK) * QKVS + INNER + hh * DHEAD;
  const unsigned short* vg = vtg + (size_t)(bb * HEADS + hh) * DHEAD * NTOK;
  unsigned short* Pw = Pl[wv];

  int srow = lane >> 3, soff = (lane & 7) * 8;
  int xs = ((lane & 7) ^ srow) * 8;      // swizzled store col
  int xq = (quad ^ (lr & 7)) * 8;        // swizzled frag-read col (s=0)

#pragma unroll
  for (int p = 0; p < 4; ++p) {
    int r = p * 8 + srow;
    *(int4*)(Pw + r * 64 + xs) = *(const int4*)(qg + (size_t)r * QKVS + soff);
  }
  short8 qf[2][2];
#pragma unroll
  for (int n = 0; n < 2; ++n)
#pragma unroll
    for (int s = 0; s < 2; ++s)
      qf[n][s] = *(const short8*)(Pw + (n * 16 + lr) * 64 + (xq ^ (s * 32)));

  v4f oac[2][4] = {};
  float m_i[2] = {-1e30f, -1e30f};
  float l_i[2] = {0.f, 0.f};

  for (int t = 0; t < NTOK / 64; ++t) {
    __syncthreads();
#pragma unroll
    for (int p = 0; p < 2; ++p) {
      int r = wv * 16 + p * 8 + srow;
      *(int4*)(Ks + r * 64 + xs) =
          *(const int4*)(kg + (size_t)(t * 64 + r) * QKVS + soff);
      *(int4*)(Vs + r * 64 + xs) =
          *(const int4*)(vg + (size_t)r * NTOK + t * 64 + soff);
    }
    __syncthreads();

    v4f sac[4][2] = {};
#pragma unroll
    for (int s = 0; s < 2; ++s) {
      short8 kf[4];
#pragma unroll
      for (int mt = 0; mt < 4; ++mt)
        kf[mt] = *(const short8*)(Ks + (mt * 16 + lr) * 64 + (xq ^ (s * 32)));
#pragma unroll
      for (int mt = 0; mt < 4; ++mt)
#pragma unroll
        for (int n = 0; n < 2; ++n)
          sac[mt][n] = __builtin_amdgcn_mfma_f32_16x16x32_bf16(
              kf[mt], qf[n][s], sac[mt][n], 0, 0, 0);
    }

#pragma unroll
    for (int n = 0; n < 2; ++n) {
      float mx = -1e30f;
#pragma unroll
      for (int mt = 0; mt < 4; ++mt)
#pragma unroll
        for (int r = 0; r < 4; ++r) mx = fmaxf(mx, sac[mt][n][r]);
      mx = fmaxf(mx, __shfl_xor(mx, 16, 64));
      mx = fmaxf(mx, __shfl_xor(mx, 32, 64));
      // defer-max: only rescale when the max grew past the threshold
      if (!__all(mx - m_i[n] <= 8.0f)) {
        float mnew = fmaxf(m_i[n], mx);
        float alpha = __builtin_amdgcn_exp2f(m_i[n] - mnew);
        m_i[n] = mnew;
        l_i[n] *= alpha;
#pragma unroll
        for (int r = 0; r < 4; ++r) {
          float ao = __shfl(alpha, quad * 4 + r, 64);
#pragma unroll
          for (int j2 = 0; j2 < 4; ++j2) oac[n][j2][r] *= ao;
        }
      }
      float sum = 0.f;
#pragma unroll
      for (int mt = 0; mt < 4; ++mt) {
#pragma unroll
        for (int r = 0; r < 4; ++r) {
          float p = __builtin_amdgcn_exp2f(sac[mt][n][r] - m_i[n]);
          sac[mt][n][r] = p;
          sum += p;
        }
        *(uint2*)(Pw + (n * 16 + lr) * 64 +
                  (((mt * 2 + (quad >> 1)) ^ (lr & 7)) * 8) + (quad & 1) * 4) =
            make_uint2(pkrh(sac[mt][n][0], sac[mt][n][1]),
                       pkrh(sac[mt][n][2], sac[mt][n][3]));
      }
      sum += __shfl_xor(sum, 16, 64);
      sum += __shfl_xor(sum, 32, 64);
      l_i[n] += sum;
    }

#pragma unroll
    for (int s = 0; s < 2; ++s) {
      short8 pf[2], vf[4];
#pragma unroll
      for (int i = 0; i < 2; ++i)
        pf[i] = *(const short8*)(Pw + (i * 16 + lr) * 64 + (xq ^ (s * 32)));
#pragma unroll
      for (int j = 0; j < 4; ++j)
        vf[j] = *(const short8*)(Vs + (j * 16 + lr) * 64 + (xq ^ (s * 32)));
#pragma unroll
      for (int i = 0; i < 2; ++i)
#pragma unroll
        for (int j = 0; j < 4; ++j)
          oac[i][j] = __builtin_amdgcn_mfma_f32_16x16x32_bf16(
              pf[i], vf[j], oac[i][j], 0, 0, 0);
    }
  }

  unsigned short* ob =
      o + (size_t)(bb * NTOK + q0 + wv * 32) * INNER + hh * DHEAD;
#pragma unroll
  for (int i = 0; i < 2; ++i) {
    float inv = 1.0f / l_i[i];
#pragma unroll
    for (int r = 0; r < 4; ++r) {
      float il = __shfl(inv, quad * 4 + r, 64);
      int row = i * 16 + quad * 4 + r;
#pragma unroll
      for (int j = 0; j < 4; ++j)
        ob[(size_t)row * INNER + 16 * j + lr] = f2b(oac[i][j][r] * il);
    }
  }
}

// ---------------------------------------------------------------------------
extern "C" void kernel_launch(void* const* d_in, const int* in_sizes, int n_in,
                              void* d_out, int out_size, void* d_ws,
                              size_t ws_size, hipStream_t stream) {
  const float* x      = (const float*)d_in[0];
  const float* w_conv = (const float*)d_in[1];
  const float* b_conv = (const float*)d_in[2];
  const float* pos    = (const float*)d_in[3];
  const float* ln1w   = (const float*)d_in[4];
  const float* ln1b   = (const float*)d_in[5];
  const float* qkvw   = (const float*)d_in[6];
  const float* outw   = (const float*)d_in[7];
  const float* outb   = (const float*)d_in[8];
  const float* ln2w   = (const float*)d_in[9];
  const float* ln2b   = (const float*)d_in[10];
  const float* w1     = (const float*)d_in[11];
  const float* b1     = (const float*)d_in[12];
  const float* w2     = (const float*)d_in[13];
  const float* b2     = (const float*)d_in[14];

  char* ws = (char*)d_ws;
  float* outp = (float*)d_out;
  dim3 blk(256);
  dim3 blk8(512);

  // Allow 128KB dynamic LDS on the 8-phase GEMM (once per process). If the
  // opt-in fails, fall back to the proven 2-barrier GEMM for qkv/mlp1 so we
  // never issue an invalid launch (graceful degradation, no process abort).
  static int use8ph = -1;
  if (use8ph < 0) {
    hipError_t e1 = hipFuncSetAttribute(
        reinterpret_cast<const void*>(&gemm8ph_kernel<5, 1>),
        hipFuncAttributeMaxDynamicSharedMemorySize, SM8PH);
    hipError_t e2 = hipFuncSetAttribute(
        reinterpret_cast<const void*>(&gemm8ph_kernel<3, 1>),
        hipFuncAttributeMaxDynamicSharedMemorySize, SM8PH);
    use8ph = (e1 == hipSuccess && e2 == hipSuccess) ? 1 : 0;
  }

  // Common buffers
  float* h            = (float*)(ws + 0);                 // 25,165,824 B
  unsigned short* big = (unsigned short*)(ws + 25165824); // 50,331,648 B
  unsigned short* y   = (unsigned short*)(ws + 75497472); // 12,582,912 B

  // Batched-weight layout (needs 214,204,416 B); fallback = per-layer.
  const size_t NEEDED = 214204416;
  bool batched = ws_size >= NEEDED;

  unsigned short *vt, *wc, *wqa, *woa, *w1a, *w2a;  // batched
  unsigned short *wq_f, *wo_f, *w1_f, *w2_f;        // fallback per-layer
  if (batched) {
    vt  = (unsigned short*)(ws + 88080384);   // 12,582,912 B
    wc  = (unsigned short*)(ws + 100663296);  //    294,912 B
    wqa = (unsigned short*)(ws + 100958208);  // 28,311,552 B
    woa = (unsigned short*)(ws + 129269760);  //  9,437,184 B
    w1a = (unsigned short*)(ws + 138706944);  // 37,748,736 B
    w2a = (unsigned short*)(ws + 176455680);  // 37,748,736 B
    wq_f = wo_f = w1_f = w2_f = nullptr;
  } else {
    wq_f = (unsigned short*)(ws + 88080384);  //  3,538,944 B
    wo_f = (unsigned short*)(ws + 91619328);  //  1,179,648 B
    w1_f = (unsigned short*)(ws + 92798976);  //  4,718,592 B
    w2_f = (unsigned short*)(ws + 97517568);  //  4,718,592 B
    wc   = (unsigned short*)(ws + 102236160); //    294,912 B
    vt   = (unsigned short*)(ws + 102531072); // 12,582,912 B
    wqa = woa = w1a = w2a = nullptr;
  }

  cast_kernel<<<dim3((DMODEL * KPATCH + 255) / 256), blk, 0, stream>>>(
      w_conv, wc, DMODEL * KPATCH);
  im2col_kernel<<<dim3((MROWS * KPATCH + 255) / 256), blk, 0, stream>>>(x, big);
  // patch embed: [8192,192] @ wc[768,192]^T + b_conv + pos -> h fp32 (K=192)
  mfma_gemm_kernel<4, 0, 64>
      <<<dim3((MROWS / 64) * (DMODEL / 128)), blk, 0, stream>>>(
          big, wc, b_conv, pos, h, MROWS, DMODEL, KPATCH);

  if (batched) {  // all-layer weight transposes, one dispatch per type
    transpose_cast_kernel<<<dim3(QKVS / 32, DMODEL / 32, DEPTH), blk, 0,
                            stream>>>(qkvw, wqa, DMODEL, QKVS);
    transpose_cast_kernel<<<dim3(DMODEL / 32, INNER / 32, DEPTH), blk, 0,
                            stream>>>(outw, woa, INNER, DMODEL);
    transpose_cast_kernel<<<dim3(MLPDIM / 32, DMODEL / 32, DEPTH), blk, 0,
                            stream>>>(w1, w1a, DMODEL, MLPDIM);
    transpose_cast_kernel<<<dim3(DMODEL / 32, MLPDIM / 32, DEPTH), blk, 0,
                            stream>>>(w2, w2a, MLPDIM, DMODEL);
  }

  for (int l = 0; l < DEPTH; ++l) {
    unsigned short* wq = batched ? wqa + (size_t)l * DMODEL * QKVS : wq_f;
    unsigned short* wo = batched ? woa + (size_t)l * INNER * DMODEL : wo_f;
    unsigned short* w1t = batched ? w1a + (size_t)l * DMODEL * MLPDIM : w1_f;
    unsigned short* w2t = batched ? w2a + (size_t)l * MLPDIM * DMODEL : w2_f;
    if (!batched) {
      transpose_cast_kernel<<<dim3(QKVS / 32, DMODEL / 32), blk, 0, stream>>>(
          qkvw + (size_t)l * DMODEL * QKVS, wq, DMODEL, QKVS);
    }
    ln_kernel<<<dim3(MROWS), blk, 0, stream>>>(h, ln1w + l * DMODEL,
                                               ln1b + l * DMODEL, y);
    if (use8ph)
      gemm8ph_kernel<5, 1>
          <<<dim3((MROWS / 256) * (QKVS / 256)), blk8, SM8PH, stream>>>(
              y, wq, nullptr, big, MROWS, QKVS, DMODEL);
    else
      mfma_gemm_kernel<5, 1, 128>
          <<<dim3((MROWS / 128) * (QKVS / 128)), blk, 0, stream>>>(
              y, wq, nullptr, nullptr, big, MROWS, QKVS, DMODEL);
    vtrans_kernel<<<dim3(NTOK / 32, DHEAD / 32, BATCH * HEADS), blk, 0,
                    stream>>>(big, vt);
    attn_kernel<<<dim3(NTOK / 128, HEADS, BATCH), blk, 0, stream>>>(big, vt, y);
    if (!batched) {
      transpose_cast_kernel<<<dim3(DMODEL / 32, INNER / 32), blk, 0, stream>>>(
          outw + (size_t)l * INNER * DMODEL, wo, INNER, DMODEL);
    }
    mfma_gemm_kernel<2, 0, 64>
        <<<dim3((MROWS / 64) * (DMODEL / 128)), blk, 0, stream>>>(
            y, wo, outb + l * DMODEL, h, h, MROWS, DMODEL, INNER);
    ln_kernel<<<dim3(MROWS), blk, 0, stream>>>(h, ln2w + l * DMODEL,
                                               ln2b + l * DMODEL, y);
    if (!batched) {
      transpose_cast_kernel<<<dim3(MLPDIM / 32, DMODEL / 32), blk, 0, stream>>>(
          w1 + (size_t)l * DMODEL * MLPDIM, w1t, DMODEL, MLPDIM);
    }
    if (use8ph)
      gemm8ph_kernel<3, 1>
          <<<dim3((MROWS / 256) * (MLPDIM / 256)), blk8, SM8PH, stream>>>(
              y, w1t, b1 + l * MLPDIM, big, MROWS, MLPDIM, DMODEL);
    else
      mfma_gemm_kernel<3, 1, 128>
          <<<dim3((MROWS / 128) * (MLPDIM / 128)), blk, 0, stream>>>(
              y, w1t, b1 + l * MLPDIM, nullptr, big, MROWS, MLPDIM, DMODEL);
    if (!batched) {
      transpose_cast_kernel<<<dim3(DMODEL / 32, MLPDIM / 32), blk, 0, stream>>>(
          w2 + (size_t)l * MLPDIM * DMODEL, w2t, MLPDIM, DMODEL);
    }
    float* dst = (l == DEPTH - 1) ? outp : h;
    mfma_gemm_kernel<2, 0, 64>
        <<<dim3((MROWS / 64) * (DMODEL / 128)), blk, 0, stream>>>(
            big, w2t, b2 + l * DMODEL, h, dst, MROWS, DMODEL, MLPDIM);
  }
}

// Round 4
// 2306.218 us; speedup vs baseline: 1.0243x; 1.0087x over previous
//
#include <hip/hip_runtime.h>
#include <math.h>

// Problem constants (ViT-Base-ish)
#define BATCH 8
#define CIN 3
#define HIMG 256
#define WIMG 256
#define PATCH 8
#define DMODEL 768
#define DEPTH 8
#define HEADS 12
#define DHEAD 64
#define MLPDIM 3072
#define NTOK 1024              // (256/8)^2
#define INNER 768              // HEADS*DHEAD
#define MROWS (BATCH * NTOK)   // 8192
#define QKVS (3 * INNER)       // 2304
#define KPATCH (CIN * PATCH * PATCH)  // 192
#define LNEPS 1e-5f
// 0.125 (dh^-0.5) * log2(e): folded into Q so softmax uses exp2 (v_exp_f32)
#define QSCALE 0.18033688011112042f

typedef __attribute__((ext_vector_type(8))) short short8;  // 8 bf16 (4 VGPRs)
typedef __attribute__((ext_vector_type(4))) float v4f;     // MFMA accumulator

__device__ __forceinline__ float b2f(unsigned short u) {
  union { unsigned int i; float f; } x;
  x.i = (unsigned int)u << 16;
  return x.f;
}
__device__ __forceinline__ unsigned short f2b(float f) {
  union { float f; unsigned int i; } x;
  x.f = f;
  unsigned int r = x.i + 0x7FFFu + ((x.i >> 16) & 1u);  // RNE
  return (unsigned short)(r >> 16);
}
// pack 2 fp32 -> 2 bf16 in one u32, round-half-up (cheap: 4 VALU)
__device__ __forceinline__ unsigned int pkrh(float a, float b) {
  union { float f; unsigned int u; } x, y;
  x.f = a; y.f = b;
  return ((x.u + 0x8000u) >> 16) | ((y.u + 0x8000u) & 0xFFFF0000u);
}

// async 16B/lane global->LDS (wave-uniform LDS base + lane*16B)
#define GLL(gp, lp)                                                     \
  __builtin_amdgcn_global_load_lds(                                     \
      (const __attribute__((address_space(1))) void*)(gp),              \
      (__attribute__((address_space(3))) void*)(lp), 16, 0, 0)

// ---------------------------------------------------------------------------
// elementwise fp32 -> bf16 cast (w_conv: [768,192] already [N,K])
__global__ __launch_bounds__(256) void cast_kernel(
    const float* __restrict__ src, unsigned short* __restrict__ dst, int n) {
  int i = blockIdx.x * 256 + threadIdx.x;
  if (i < n) dst[i] = f2b(src[i]);
}

// transpose-cast: src fp32 [R,C] -> dst bf16 [C,R]. R,C multiples of 32.
// blockIdx.z selects a layer: both src and dst advance by R*C elements.
__global__ __launch_bounds__(256) void transpose_cast_kernel(
    const float* __restrict__ src, unsigned short* __restrict__ dst, int R,
    int C) {
  __shared__ unsigned short t[32][33];
  src += (size_t)blockIdx.z * R * C;
  dst += (size_t)blockIdx.z * R * C;
  int c0 = blockIdx.x * 32, r0 = blockIdx.y * 32;
  int tx = threadIdx.x & 31, ty = threadIdx.x >> 5;  // 32 x 8
#pragma unroll
  for (int u = 0; u < 4; ++u) {
    int r = r0 + ty + u * 8;
    t[ty + u * 8][tx] = f2b(src[(size_t)r * C + c0 + tx]);
  }
  __syncthreads();
#pragma unroll
  for (int u = 0; u < 4; ++u) {
    int c = c0 + ty + u * 8;
    dst[(size_t)c * R + r0 + tx] = t[tx][ty + u * 8];
  }
}

// V transpose per layer: qkv bf16 [MROWS][QKVS] V-part -> vt [B*H][64][1024]
__global__ __launch_bounds__(256) void vtrans_kernel(
    const unsigned short* __restrict__ qkv, unsigned short* __restrict__ vt) {
  __shared__ unsigned short t[32][33];
  int k0 = blockIdx.x * 32;   // key tile
  int d0 = blockIdx.y * 32;   // dim tile within head
  int bh = blockIdx.z;        // b*HEADS+h
  int b = bh / HEADS, h = bh % HEADS;
  int tx = threadIdx.x & 31, ty = threadIdx.x >> 5;
  const unsigned short* src =
      qkv + (size_t)(b * NTOK) * QKVS + 2 * INNER + h * DHEAD;
#pragma unroll
  for (int u = 0; u < 4; ++u)
    t[ty + u * 8][tx] = src[(size_t)(k0 + ty + u * 8) * QKVS + d0 + tx];
  __syncthreads();
  unsigned short* dst = vt + ((size_t)bh * DHEAD + d0) * NTOK + k0;
#pragma unroll
  for (int u = 0; u < 4; ++u)
    dst[(size_t)(ty + u * 8) * NTOK + tx] = t[tx][ty + u * 8];
}

// im2col -> bf16: x [B,C,H,W] -> A [MROWS, 192]
__global__ __launch_bounds__(256) void im2col_kernel(
    const float* __restrict__ x, unsigned short* __restrict__ A) {
  int idx = blockIdx.x * 256 + threadIdx.x;
  if (idx >= MROWS * KPATCH) return;
  int m = idx / KPATCH, k = idx % KPATCH;
  int b = m / NTOK, n = m % NTOK;
  int ph = n / 32, pw = n % 32;
  int c = k / 64, r = k % 64;
  int py = r / 8, px = r % 8;
  A[idx] =
      f2b(x[((size_t)(b * CIN + c) * HIMG + ph * 8 + py) * WIMG + pw * 8 + px]);
}

// ---------------------------------------------------------------------------
// Proven 2-barrier bf16 MFMA GEMM (3 blocks/CU). Used for patch embed and the
// N=768 GEMMs (out-proj, mlp2) where 256-wide tiles would idle 25% of CUs.
// Also the fallback for qkv/mlp1 if the 128KB dynamic-LDS opt-in fails.
template <int EPI, int OB, int MT>
__global__ __launch_bounds__(256) void mfma_gemm_kernel(
    const unsigned short* __restrict__ Ag, const unsigned short* __restrict__ Bt,
    const float* __restrict__ bias, const float* __restrict__ res,
    void* __restrict__ Cg, int Mdim, int Ndim, int Kdim) {
  constexpr int MI = MT / 32;               // m fragment tiles per wave (4|2)
  constexpr int RA = MT / 4;                // A rows staged per wave (32|16)
  constexpr int NCA = RA / 8;               // A GLL chunks per wave (4|2)
  __shared__ __align__(16) unsigned short Asm[MT * 64];
  __shared__ __align__(16) unsigned short Bsm[128 * 64];
  int tid = threadIdx.x;
  int lane = tid & 63, wv = tid >> 6;

  // XCD-aware swizzle (1-D grid of (M/MT)*(N/128) blocks)
  int Nt = Ndim / 128;
  int mchunk = (Mdim / MT) >> 3;
  int bid = blockIdx.x;
  int xcd = bid & 7;
  int j = bid >> 3;
  int m0 = (xcd * mchunk + j / Nt) * MT;
  int n0 = (j % Nt) * 128;

  v4f acc[MI][4] = {};

  int sr8 = lane >> 3;
  int sc8 = ((lane & 7) ^ sr8) * 8;
  const unsigned short* Aw = Ag + (size_t)(m0 + RA * wv + sr8) * Kdim + sc8;
  const unsigned short* Bw = Bt + (size_t)(n0 + 32 * wv + sr8) * Kdim + sc8;
  unsigned short* As0 = Asm + (RA * wv) * 64;
  unsigned short* Bs0 = Bsm + (32 * wv) * 64;

  int quad = lane >> 4, lr = lane & 15;
  int fr0 = (wv >> 1) * (MI * 16);
  int fc0 = (wv & 1) * 64;
  int xcol = (quad ^ (lr & 7)) * 8;  // swizzled col offset (s=0); s=1: ^32
  const unsigned short* Afr = Asm + (fr0 + lr) * 64;
  const unsigned short* Bfr = Bsm + (fc0 + lr) * 64;

  for (int k0 = 0; k0 < Kdim; k0 += 64) {
#pragma unroll
    for (int c = 0; c < NCA; ++c)
      GLL(Aw + k0 + (size_t)(8 * c) * Kdim, As0 + c * 8 * 64);
#pragma unroll
    for (int c = 0; c < 4; ++c)
      GLL(Bw + k0 + (size_t)(8 * c) * Kdim, Bs0 + c * 8 * 64);
    __syncthreads();
#pragma unroll
    for (int s = 0; s < 2; ++s) {
      int xo = xcol ^ (s * 32);
      short8 af[MI], bf[4];
#pragma unroll
      for (int i = 0; i < MI; ++i)
        af[i] = *(const short8*)(Afr + i * 16 * 64 + xo);
#pragma unroll
      for (int n = 0; n < 4; ++n)
        bf[n] = *(const short8*)(Bfr + n * 16 * 64 + xo);
#pragma unroll
      for (int i = 0; i < MI; ++i)
#pragma unroll
        for (int n = 0; n < 4; ++n)
          acc[i][n] = __builtin_amdgcn_mfma_f32_16x16x32_bf16(
              af[i], bf[n], acc[i][n], 0, 0, 0);
    }
    __syncthreads();
  }

  float* Cf = (float*)Cg;
  unsigned short* Cb = (unsigned short*)Cg;
#pragma unroll
  for (int i = 0; i < MI; ++i) {
#pragma unroll
    for (int n = 0; n < 4; ++n) {
      int ncol = n0 + fc0 + 16 * n + lr;
#pragma unroll
      for (int reg = 0; reg < 4; ++reg) {
        int mrow = m0 + fr0 + 16 * i + quad * 4 + reg;
        float v = acc[i][n][reg];
        if (EPI == 2 || EPI == 3 || EPI == 4) v += bias[ncol];
        if (EPI == 2) v += res[(size_t)mrow * Ndim + ncol];
        if (EPI == 3) {
          float u = v * (0.7978845608028654f + 0.035677408136300125f * v * v);
          float a = fminf(fmaxf(u * 2.8853900817779268f, -60.f), 60.f);
          float E = __builtin_amdgcn_exp2f(a);
          v = v * E * __builtin_amdgcn_rcpf(E + 1.0f);
        }
        if (EPI == 4) v += res[(size_t)(mrow % NTOK) * Ndim + ncol];
        if (EPI == 5 && ncol < INNER) v *= QSCALE;
        if (OB)
          Cb[(size_t)mrow * Ndim + ncol] = f2b(v);
        else
          Cf[(size_t)mrow * Ndim + ncol] = v;
      }
    }
  }
}

// ---------------------------------------------------------------------------
// m201-style 8-phase 256x256 GEMM (frozen this round; see round-3 comments
// for the schedule-safety derivation). qkv + mlp1 only.
#define ABUF8 (256 * 64)
#define BBUF8 (256 * 64)
#define SM8PH (2 * (ABUF8 + BBUF8) * 2)  // 131072 bytes dynamic LDS

template <int EPI, int OB>
__global__ __launch_bounds__(512, 2) void gemm8ph_kernel(
    const unsigned short* __restrict__ Ag, const unsigned short* __restrict__ Bt,
    const float* __restrict__ bias, void* __restrict__ Cg, int Mdim, int Ndim,
    int Kdim) {
  extern __shared__ __align__(16) unsigned short sm8[];
  unsigned short* As = sm8;               // [2][256][64]
  unsigned short* Bs = sm8 + 2 * ABUF8;   // [2][256][64]
  int tid = threadIdx.x;
  int lane = tid & 63, wv = tid >> 6;
  int wm = wv >> 2, wn = wv & 3;          // 2M x 4N wave grid
  int quad = lane >> 4, lr = lane & 15;

  int Nt = Ndim >> 8;
  int mchunk = (Mdim >> 8) >> 3;
  int bid = blockIdx.x;
  int xcd = bid & 7, j = bid >> 3;
  int m0 = (xcd * mchunk + j / Nt) << 8;
  int n0 = (j % Nt) << 8;
  int NTI = Kdim >> 6;  // K-tiles, even, >= 4

  int sr8 = lane >> 3;
  int sc8 = ((lane & 7) ^ sr8) * 8;
  const unsigned short* Aw = Ag + (size_t)(m0 + wv * 8 + sr8) * Kdim + sc8;
  const unsigned short* Bw = Bt + (size_t)(n0 + wv * 8 + sr8) * Kdim + sc8;
  unsigned short* AsW = As + (wv * 8) * 64;
  unsigned short* BsW = Bs + (wv * 8) * 64;

  int xq = (quad ^ (lr & 7)) * 8;
  const unsigned short* Afr = As + (wm * 128 + lr) * 64;   // buf0
  const unsigned short* Bfr = Bs + (wn * 64 + lr) * 64;    // buf0
  const unsigned short* Afr1 = Afr + ABUF8;                // buf1
  const unsigned short* Bfr1 = Bfr + BBUF8;                // buf1

  v4f acc[8][4] = {};
  short8 af[2][4], bf0[2][2], bf1[2][2];

#define STG_A8(buf, tile, half)                                           \
  do {                                                                    \
    GLL(Aw + (size_t)((half) * 128) * Kdim + (tile) * 64,                 \
        AsW + (buf) * ABUF8 + ((half) * 128) * 64);                       \
    GLL(Aw + (size_t)((half) * 128 + 64) * Kdim + (tile) * 64,            \
        AsW + (buf) * ABUF8 + ((half) * 128 + 64) * 64);                  \
  } while (0)
#define STG_B8(buf, tile, half)                                           \
  do {                                                                    \
    GLL(Bw + (size_t)((half) * 128) * Kdim + (tile) * 64,                 \
        BsW + (buf) * BBUF8 + ((half) * 128) * 64);                       \
    GLL(Bw + (size_t)((half) * 128 + 64) * Kdim + (tile) * 64,            \
        BsW + (buf) * BBUF8 + ((half) * 128 + 64) * 64);                  \
  } while (0)

  auto rd_af = [&](const unsigned short* base, int mb) {
#pragma unroll
    for (int s = 0; s < 2; ++s)
#pragma unroll
      for (int m = 0; m < 4; ++m)
        af[s][m] =
            *(const short8*)(base + (mb + m * 16) * 64 + (xq ^ (s * 32)));
  };
  auto rd_bf0 = [&](const unsigned short* base, int nb) {
#pragma unroll
    for (int s = 0; s < 2; ++s)
#pragma unroll
      for (int n = 0; n < 2; ++n)
        bf0[s][n] =
            *(const short8*)(base + (nb + n * 16) * 64 + (xq ^ (s * 32)));
  };
  auto rd_bf1 = [&](const unsigned short* base, int nb) {
#pragma unroll
    for (int s = 0; s < 2; ++s)
#pragma unroll
      for (int n = 0; n < 2; ++n)
        bf1[s][n] =
            *(const short8*)(base + (nb + n * 16) * 64 + (xq ^ (s * 32)));
  };
  auto mfma0 = [&](int mb, int nb) {  // af x bf0
#pragma unroll
    for (int s = 0; s < 2; ++s)
#pragma unroll
      for (int m = 0; m < 4; ++m)
#pragma unroll
        for (int n = 0; n < 2; ++n)
          acc[mb + m][nb + n] = __builtin_amdgcn_mfma_f32_16x16x32_bf16(
              af[s][m], bf0[s][n], acc[mb + m][nb + n], 0, 0, 0);
  };
  auto mfma1 = [&](int mb, int nb) {  // af x bf1
#pragma unroll
    for (int s = 0; s < 2; ++s)
#pragma unroll
      for (int m = 0; m < 4; ++m)
#pragma unroll
        for (int n = 0; n < 2; ++n)
          acc[mb + m][nb + n] = __builtin_amdgcn_mfma_f32_16x16x32_bf16(
              af[s][m], bf1[s][n], acc[mb + m][nb + n], 0, 0, 0);
  };
  auto mfma_begin = [&]() {
    __builtin_amdgcn_s_barrier();
    asm volatile("s_waitcnt lgkmcnt(0)" ::: "memory");
    __builtin_amdgcn_sched_barrier(0);
    __builtin_amdgcn_s_setprio(1);
  };
  auto mfma_end = [&]() {
    __builtin_amdgcn_s_setprio(0);
    __builtin_amdgcn_s_barrier();
  };

  // prologue: tile0 -> buf0 (B0,B1,A0,A1); tile1 B -> buf1 (B0,B1)
  STG_B8(0, 0, 0);
  STG_B8(0, 0, 1);
  STG_A8(0, 0, 0);
  STG_A8(0, 0, 1);
  STG_B8(1, 1, 0);
  STG_B8(1, 1, 1);
  asm volatile("s_waitcnt vmcnt(4)" ::: "memory");  // tile0 landed
  __builtin_amdgcn_s_barrier();

  int NI = NTI >> 1;
  for (int i = 0; i < NI; ++i) {
    int t1 = 2 * i + 1, t2 = 2 * i + 2, t3 = 2 * i + 3;
    bool st = t2 < NTI;

    // ---- phase 1 ----
    rd_af(Afr, 0);
    rd_bf0(Bfr, 0);
    STG_A8(1, t1, 0);
    mfma_begin();
    mfma0(0, 0);
    mfma_end();
    // ---- phase 2 ----
    rd_bf1(Bfr, 32);
    STG_A8(1, t1, 1);
    mfma_begin();
    mfma1(0, 2);
    mfma_end();
    // ---- phase 3 ----
    rd_af(Afr, 64);
    if (st) STG_B8(0, t2, 0);
    mfma_begin();
    mfma0(4, 0);
    mfma_end();
    // ---- phase 4 ----
    if (st) {
      STG_B8(0, t2, 1);
      asm volatile("s_waitcnt vmcnt(4)" ::: "memory");  // tile t1 landed
    } else {
      asm volatile("s_waitcnt vmcnt(0)" ::: "memory");  // tail drain
    }
    mfma_begin();
    mfma1(4, 2);
    mfma_end();
    // ---- phase 5 ----
    rd_af(Afr1, 0);
    rd_bf0(Bfr1, 0);
    if (st) STG_A8(0, t2, 0);
    mfma_begin();
    mfma0(0, 0);
    mfma_end();
    // ---- phase 6 ----
    rd_bf1(Bfr1, 32);
    if (st) STG_A8(0, t2, 1);
    mfma_begin();
    mfma1(0, 2);
    mfma_end();
    // ---- phase 7 ----
    rd_af(Afr1, 64);
    if (st) STG_B8(1, t3, 0);
    mfma_begin();
    mfma0(4, 0);
    mfma_end();
    // ---- phase 8 ----
    if (st) {
      STG_B8(1, t3, 1);
      asm volatile("s_waitcnt vmcnt(4)" ::: "memory");  // tile t2 landed
    }
    mfma_begin();
    mfma1(4, 2);
    mfma_end();
  }
#undef STG_A8
#undef STG_B8

  // epilogue: C/D layout col=lane&15, row=quad*4+reg
  float* Cf = (float*)Cg;
  unsigned short* Cb = (unsigned short*)Cg;
#pragma unroll
  for (int i = 0; i < 8; ++i) {
#pragma unroll
    for (int n = 0; n < 4; ++n) {
      int ncol = n0 + wn * 64 + 16 * n + lr;
#pragma unroll
      for (int reg = 0; reg < 4; ++reg) {
        int mrow = m0 + wm * 128 + 16 * i + quad * 4 + reg;
        float v = acc[i][n][reg];
        if (EPI == 3) {
          v += bias[ncol];
          float u = v * (0.7978845608028654f + 0.035677408136300125f * v * v);
          float a = fminf(fmaxf(u * 2.8853900817779268f, -60.f), 60.f);
          float E = __builtin_amdgcn_exp2f(a);
          v = v * E * __builtin_amdgcn_rcpf(E + 1.0f);
        }
        if (EPI == 5 && ncol < INNER) v *= QSCALE;
        if (OB)
          Cb[(size_t)mrow * Ndim + ncol] = f2b(v);
        else
          Cf[(size_t)mrow * Ndim + ncol] = v;
      }
    }
  }
}

// ---------------------------------------------------------------------------
// LayerNorm over last dim (768), fp32 in -> bf16 out. One block per row.
__global__ __launch_bounds__(256) void ln_kernel(
    const float* __restrict__ x, const float* __restrict__ w,
    const float* __restrict__ b, unsigned short* __restrict__ y) {
  int row = blockIdx.x;
  const float* xr = x + (size_t)row * DMODEL;
  unsigned short* yr = y + (size_t)row * DMODEL;
  int tid = threadIdx.x;
  float v0 = xr[tid], v1 = xr[tid + 256], v2 = xr[tid + 512];
  float s = v0 + v1 + v2;
  __shared__ float red[4];
#pragma unroll
  for (int off = 32; off >= 1; off >>= 1) s += __shfl_xor(s, off, 64);
  if ((tid & 63) == 0) red[tid >> 6] = s;
  __syncthreads();
  float mean = (red[0] + red[1] + red[2] + red[3]) * (1.0f / DMODEL);
  float d0 = v0 - mean, d1 = v1 - mean, d2 = v2 - mean;
  float sq = d0 * d0 + d1 * d1 + d2 * d2;
  __syncthreads();
#pragma unroll
  for (int off = 32; off >= 1; off >>= 1) sq += __shfl_xor(sq, off, 64);
  if ((tid & 63) == 0) red[tid >> 6] = sq;
  __syncthreads();
  float var = (red[0] + red[1] + red[2] + red[3]) * (1.0f / DMODEL);
  float rs = rsqrtf(var + LNEPS);
  yr[tid] = f2b(d0 * rs * w[tid] + b[tid]);
  yr[tid + 256] = f2b(d1 * rs * w[tid + 256] + b[tid + 256]);
  yr[tid + 512] = f2b(d2 * rs * w[tid + 512] + b[tid + 512]);
}

// ---------------------------------------------------------------------------
// MFMA flash attention, round 4:
//  * XCD-bijective grid (1-D, 768): xcd=bid&7 owns heads xcd*12..+11, so all
//    8 q-blocks of a head share one XCD's L2 (12 heads x 256KB K/V = 3MB < 4MB)
//    -> kills the 2.8x HBM over-fetch (104.5MB -> ~40MB measured FETCH).
//  * Async double-buffered K/V staging via global_load_lds: issue tile t+1's
//    4 GLL into buf^1, compute tile t, vmcnt(0) + ONE barrier per tile. The
//    ~200-900cy load latency hides under a full tile of MFMA+softmax.
//    GLL's linear LDS dest reproduces the swizzled layout by pre-swizzling
//    the global source col ((lane&7)^(lane>>3))*8 — identical content to the
//    old int4 store path; all fragment reads unchanged.
//  * defer-max (T13) kept from round 3.
__global__ __launch_bounds__(256) void attn_kernel(
    const unsigned short* __restrict__ qkv,
    const unsigned short* __restrict__ vtg, unsigned short* __restrict__ o) {
  __shared__ __align__(16) unsigned short Ks[2][64 * 64];
  __shared__ __align__(16) unsigned short Vs[2][64 * 64];
  __shared__ __align__(16) unsigned short Pl[4][32 * 64];
  int tid = threadIdx.x;
  int lane = tid & 63, wv = tid >> 6;
  int quad = lane >> 4, lr = lane & 15;

  // XCD-bijective mapping: head-group per XCD, q-block slowest within XCD
  int bid = blockIdx.x;
  int xcd = bid & 7, j = bid >> 3;     // j in 0..95
  int hl = xcd * 12 + (j % 12);        // b*HEADS+h in 0..95
  int qb = j / 12;                     // q-block 0..7
  int q0 = qb * 128, hh = hl % HEADS, bb = hl / HEADS;

  const unsigned short* qg =
      qkv + (size_t)(bb * NTOK + q0 + wv * 32) * QKVS + hh * DHEAD;
  const unsigned short* kg =
      qkv + (size_t)(bb * NTOK) * QKVS + INNER + hh * DHEAD;
  const unsigned short* vg = vtg + (size_t)(bb * HEADS + hh) * DHEAD * NTOK;
  unsigned short* Pw = Pl[wv];

  int srow = lane >> 3, soff = (lane & 7) * 8;
  int xs = ((lane & 7) ^ srow) * 8;    // swizzled col (store and GLL source)
  int xq = (quad ^ (lr & 7)) * 8;      // swizzled frag-read col (s=0)

  // K/V async staging: 4 GLL per wave per tile; wave wv stages rows
  // wv*16+p*8+{0..7}; LDS dest linear (base+lane*16B), source col = xs.
#define STG_KV(buf, t)                                                    \
  do {                                                                    \
    _Pragma("unroll") for (int p = 0; p < 2; ++p) {                       \
      int rr = wv * 16 + p * 8;                                           \
      GLL(kg + (size_t)((t) * 64 + rr + srow) * QKVS + xs,                \
          &Ks[buf][rr * 64]);                                             \
      GLL(vg + (size_t)(rr + srow) * NTOK + (t) * 64 + xs,                \
          &Vs[buf][rr * 64]);                                             \
    }                                                                     \
  } while (0)

  // Q -> per-wave LDS (A-fragment layout), then fragments
#pragma unroll
  for (int p = 0; p < 4; ++p) {
    int r = p * 8 + srow;
    *(int4*)(Pw + r * 64 + xs) = *(const int4*)(qg + (size_t)r * QKVS + soff);
  }
  short8 qf[2][2];
#pragma unroll
  for (int n = 0; n < 2; ++n)
#pragma unroll
    for (int s = 0; s < 2; ++s)
      qf[n][s] = *(const short8*)(Pw + (n * 16 + lr) * 64 + (xq ^ (s * 32)));

  v4f oac[2][4] = {};
  float m_i[2] = {-1e30f, -1e30f};
  float l_i[2] = {0.f, 0.f};

  // prologue: stage tile 0 into buf0
  STG_KV(0, 0);
  asm volatile("s_waitcnt vmcnt(0)" ::: "memory");
  __syncthreads();

  int cur = 0;
  for (int t = 0; t < NTOK / 64; ++t) {
    // issue next tile's loads (hidden under this tile's compute)
    if (t < NTOK / 64 - 1) STG_KV(cur ^ 1, t + 1);
    const unsigned short* Kc = Ks[cur];
    const unsigned short* Vc = Vs[cur];

    v4f sac[4][2] = {};
#pragma unroll
    for (int s = 0; s < 2; ++s) {
      short8 kf[4];
#pragma unroll
      for (int mt = 0; mt < 4; ++mt)
        kf[mt] = *(const short8*)(Kc + (mt * 16 + lr) * 64 + (xq ^ (s * 32)));
#pragma unroll
      for (int mt = 0; mt < 4; ++mt)
#pragma unroll
        for (int n = 0; n < 2; ++n)
          sac[mt][n] = __builtin_amdgcn_mfma_f32_16x16x32_bf16(
              kf[mt], qf[n][s], sac[mt][n], 0, 0, 0);
    }

#pragma unroll
    for (int n = 0; n < 2; ++n) {
      float mx = -1e30f;
#pragma unroll
      for (int mt = 0; mt < 4; ++mt)
#pragma unroll
        for (int r = 0; r < 4; ++r) mx = fmaxf(mx, sac[mt][n][r]);
      mx = fmaxf(mx, __shfl_xor(mx, 16, 64));
      mx = fmaxf(mx, __shfl_xor(mx, 32, 64));
      // defer-max: only rescale when the max grew past the threshold
      if (!__all(mx - m_i[n] <= 8.0f)) {
        float mnew = fmaxf(m_i[n], mx);
        float alpha = __builtin_amdgcn_exp2f(m_i[n] - mnew);
        m_i[n] = mnew;
        l_i[n] *= alpha;
#pragma unroll
        for (int r = 0; r < 4; ++r) {
          float ao = __shfl(alpha, quad * 4 + r, 64);
#pragma unroll
          for (int j2 = 0; j2 < 4; ++j2) oac[n][j2][r] *= ao;
        }
      }
      float sum = 0.f;
#pragma unroll
      for (int mt = 0; mt < 4; ++mt) {
#pragma unroll
        for (int r = 0; r < 4; ++r) {
          float p = __builtin_amdgcn_exp2f(sac[mt][n][r] - m_i[n]);
          sac[mt][n][r] = p;
          sum += p;
        }
        *(uint2*)(Pw + (n * 16 + lr) * 64 +
                  (((mt * 2 + (quad >> 1)) ^ (lr & 7)) * 8) + (quad & 1) * 4) =
            make_uint2(pkrh(sac[mt][n][0], sac[mt][n][1]),
                       pkrh(sac[mt][n][2], sac[mt][n][3]));
      }
      sum += __shfl_xor(sum, 16, 64);
      sum += __shfl_xor(sum, 32, 64);
      l_i[n] += sum;
    }

#pragma unroll
    for (int s = 0; s < 2; ++s) {
      short8 pf[2], vf[4];
#pragma unroll
      for (int i = 0; i < 2; ++i)
        pf[i] = *(const short8*)(Pw + (i * 16 + lr) * 64 + (xq ^ (s * 32)));
#pragma unroll
      for (int j2 = 0; j2 < 4; ++j2)
        vf[j2] = *(const short8*)(Vc + (j2 * 16 + lr) * 64 + (xq ^ (s * 32)));
#pragma unroll
      for (int i = 0; i < 2; ++i)
#pragma unroll
        for (int j2 = 0; j2 < 4; ++j2)
          oac[i][j2] = __builtin_amdgcn_mfma_f32_16x16x32_bf16(
              pf[i], vf[j2], oac[i][j2], 0, 0, 0);
    }

    // own GLLs landed + all waves done reading this buffer
    asm volatile("s_waitcnt vmcnt(0)" ::: "memory");
    __syncthreads();
    cur ^= 1;
  }
#undef STG_KV

  unsigned short* ob =
      o + (size_t)(bb * NTOK + q0 + wv * 32) * INNER + hh * DHEAD;
#pragma unroll
  for (int i = 0; i < 2; ++i) {
    float inv = 1.0f / l_i[i];
#pragma unroll
    for (int r = 0; r < 4; ++r) {
      float il = __shfl(inv, quad * 4 + r, 64);
      int row = i * 16 + quad * 4 + r;
#pragma unroll
      for (int j2 = 0; j2 < 4; ++j2)
        ob[(size_t)row * INNER + 16 * j2 + lr] = f2b(oac[i][j2][r] * il);
    }
  }
}

// ---------------------------------------------------------------------------
extern "C" void kernel_launch(void* const* d_in, const int* in_sizes, int n_in,
                              void* d_out, int out_size, void* d_ws,
                              size_t ws_size, hipStream_t stream) {
  const float* x      = (const float*)d_in[0];
  const float* w_conv = (const float*)d_in[1];
  const float* b_conv = (const float*)d_in[2];
  const float* pos    = (const float*)d_in[3];
  const float* ln1w   = (const float*)d_in[4];
  const float* ln1b   = (const float*)d_in[5];
  const float* qkvw   = (const float*)d_in[6];
  const float* outw   = (const float*)d_in[7];
  const float* outb   = (const float*)d_in[8];
  const float* ln2w   = (const float*)d_in[9];
  const float* ln2b   = (const float*)d_in[10];
  const float* w1     = (const float*)d_in[11];
  const float* b1     = (const float*)d_in[12];
  const float* w2     = (const float*)d_in[13];
  const float* b2     = (const float*)d_in[14];

  char* ws = (char*)d_ws;
  float* outp = (float*)d_out;
  dim3 blk(256);
  dim3 blk8(512);

  // Allow 128KB dynamic LDS on the 8-phase GEMM (once per process). If the
  // opt-in fails, fall back to the proven 2-barrier GEMM for qkv/mlp1 so we
  // never issue an invalid launch (graceful degradation, no process abort).
  static int use8ph = -1;
  if (use8ph < 0) {
    hipError_t e1 = hipFuncSetAttribute(
        reinterpret_cast<const void*>(&gemm8ph_kernel<5, 1>),
        hipFuncAttributeMaxDynamicSharedMemorySize, SM8PH);
    hipError_t e2 = hipFuncSetAttribute(
        reinterpret_cast<const void*>(&gemm8ph_kernel<3, 1>),
        hipFuncAttributeMaxDynamicSharedMemorySize, SM8PH);
    use8ph = (e1 == hipSuccess && e2 == hipSuccess) ? 1 : 0;
  }

  // Common buffers
  float* h            = (float*)(ws + 0);                 // 25,165,824 B
  unsigned short* big = (unsigned short*)(ws + 25165824); // 50,331,648 B
  unsigned short* y   = (unsigned short*)(ws + 75497472); // 12,582,912 B

  // Batched-weight layout (needs 214,204,416 B); fallback = per-layer.
  const size_t NEEDED = 214204416;
  bool batched = ws_size >= NEEDED;

  unsigned short *vt, *wc, *wqa, *woa, *w1a, *w2a;  // batched
  unsigned short *wq_f, *wo_f, *w1_f, *w2_f;        // fallback per-layer
  if (batched) {
    vt  = (unsigned short*)(ws + 88080384);   // 12,582,912 B
    wc  = (unsigned short*)(ws + 100663296);  //    294,912 B
    wqa = (unsigned short*)(ws + 100958208);  // 28,311,552 B
    woa = (unsigned short*)(ws + 129269760);  //  9,437,184 B
    w1a = (unsigned short*)(ws + 138706944);  // 37,748,736 B
    w2a = (unsigned short*)(ws + 176455680);  // 37,748,736 B
    wq_f = wo_f = w1_f = w2_f = nullptr;
  } else {
    wq_f = (unsigned short*)(ws + 88080384);  //  3,538,944 B
    wo_f = (unsigned short*)(ws + 91619328);  //  1,179,648 B
    w1_f = (unsigned short*)(ws + 92798976);  //  4,718,592 B
    w2_f = (unsigned short*)(ws + 97517568);  //  4,718,592 B
    wc   = (unsigned short*)(ws + 102236160); //    294,912 B
    vt   = (unsigned short*)(ws + 102531072); // 12,582,912 B
    wqa = woa = w1a = w2a = nullptr;
  }

  cast_kernel<<<dim3((DMODEL * KPATCH + 255) / 256), blk, 0, stream>>>(
      w_conv, wc, DMODEL * KPATCH);
  im2col_kernel<<<dim3((MROWS * KPATCH + 255) / 256), blk, 0, stream>>>(x, big);
  // patch embed: [8192,192] @ wc[768,192]^T + b_conv + pos -> h fp32 (K=192)
  mfma_gemm_kernel<4, 0, 64>
      <<<dim3((MROWS / 64) * (DMODEL / 128)), blk, 0, stream>>>(
          big, wc, b_conv, pos, h, MROWS, DMODEL, KPATCH);

  if (batched) {  // all-layer weight transposes, one dispatch per type
    transpose_cast_kernel<<<dim3(QKVS / 32, DMODEL / 32, DEPTH), blk, 0,
                            stream>>>(qkvw, wqa, DMODEL, QKVS);
    transpose_cast_kernel<<<dim3(DMODEL / 32, INNER / 32, DEPTH), blk, 0,
                            stream>>>(outw, woa, INNER, DMODEL);
    transpose_cast_kernel<<<dim3(MLPDIM / 32, DMODEL / 32, DEPTH), blk, 0,
                            stream>>>(w1, w1a, DMODEL, MLPDIM);
    transpose_cast_kernel<<<dim3(DMODEL / 32, MLPDIM / 32, DEPTH), blk, 0,
                            stream>>>(w2, w2a, MLPDIM, DMODEL);
  }

  for (int l = 0; l < DEPTH; ++l) {
    unsigned short* wq = batched ? wqa + (size_t)l * DMODEL * QKVS : wq_f;
    unsigned short* wo = batched ? woa + (size_t)l * INNER * DMODEL : wo_f;
    unsigned short* w1t = batched ? w1a + (size_t)l * DMODEL * MLPDIM : w1_f;
    unsigned short* w2t = batched ? w2a + (size_t)l * MLPDIM * DMODEL : w2_f;
    if (!batched) {
      transpose_cast_kernel<<<dim3(QKVS / 32, DMODEL / 32), blk, 0, stream>>>(
          qkvw + (size_t)l * DMODEL * QKVS, wq, DMODEL, QKVS);
    }
    ln_kernel<<<dim3(MROWS), blk, 0, stream>>>(h, ln1w + l * DMODEL,
                                               ln1b + l * DMODEL, y);
    if (use8ph)
      gemm8ph_kernel<5, 1>
          <<<dim3((MROWS / 256) * (QKVS / 256)), blk8, SM8PH, stream>>>(
              y, wq, nullptr, big, MROWS, QKVS, DMODEL);
    else
      mfma_gemm_kernel<5, 1, 128>
          <<<dim3((MROWS / 128) * (QKVS / 128)), blk, 0, stream>>>(
              y, wq, nullptr, nullptr, big, MROWS, QKVS, DMODEL);
    vtrans_kernel<<<dim3(NTOK / 32, DHEAD / 32, BATCH * HEADS), blk, 0,
                    stream>>>(big, vt);
    attn_kernel<<<dim3((NTOK / 128) * HEADS * BATCH), blk, 0, stream>>>(
        big, vt, y);
    if (!batched) {
      transpose_cast_kernel<<<dim3(DMODEL / 32, INNER / 32), blk, 0, stream>>>(
          outw + (size_t)l * INNER * DMODEL, wo, INNER, DMODEL);
    }
    mfma_gemm_kernel<2, 0, 64>
        <<<dim3((MROWS / 64) * (DMODEL / 128)), blk, 0, stream>>>(
            y, wo, outb + l * DMODEL, h, h, MROWS, DMODEL, INNER);
    ln_kernel<<<dim3(MROWS), blk, 0, stream>>>(h, ln2w + l * DMODEL,
                                               ln2b + l * DMODEL, y);
    if (!batched) {
      transpose_cast_kernel<<<dim3(MLPDIM / 32, DMODEL / 32), blk, 0, stream>>>(
          w1 + (size_t)l * DMODEL * MLPDIM, w1t, DMODEL, MLPDIM);
    }
    if (use8ph)
      gemm8ph_kernel<3, 1>
          <<<dim3((MROWS / 256) * (MLPDIM / 256)), blk8, SM8PH, stream>>>(
              y, w1t, b1 + l * MLPDIM, big, MROWS, MLPDIM, DMODEL);
    else
      mfma_gemm_kernel<3, 1, 128>
          <<<dim3((MROWS / 128) * (MLPDIM / 128)), blk, 0, stream>>>(
              y, w1t, b1 + l * MLPDIM, nullptr, big, MROWS, MLPDIM, DMODEL);
    if (!batched) {
      transpose_cast_kernel<<<dim3(DMODEL / 32, MLPDIM / 32), blk, 0, stream>>>(
          w2 + (size_t)l * MLPDIM * DMODEL, w2t, MLPDIM, DMODEL);
    }
    float* dst = (l == DEPTH - 1) ? outp : h;
    mfma_gemm_kernel<2, 0, 64>
        <<<dim3((MROWS / 64) * (DMODEL / 128)), blk, 0, stream>>>(
            big, w2t, b2 + l * DMODEL, h, dst, MROWS, DMODEL, MLPDIM);
  }
}